// Round 3
// baseline (497.970 us; speedup 1.0000x reference)
//
#include <hip/hip_runtime.h>

typedef unsigned short u16;
typedef unsigned char u8;
typedef __bf16 bf16x8 __attribute__((ext_vector_type(8)));
typedef float f32x4 __attribute__((ext_vector_type(4)));
typedef int i32x4 __attribute__((ext_vector_type(4)));
typedef int i32x8 __attribute__((ext_vector_type(8)));

__device__ __forceinline__ u16 f2bf(float f) {
    unsigned u = __float_as_uint(f);
    unsigned r = (u + 0x7fffu + ((u >> 16) & 1u)) >> 16;
    return (u16)r;
}
__device__ __forceinline__ float bf2f(u16 h) {
    return __uint_as_float(((unsigned)h) << 16);
}
// pack two floats to bf16x2 (lo in low half), round-half-up, single v_perm
__device__ __forceinline__ unsigned pack_bf2(float lo, float hi) {
    unsigned a = __float_as_uint(hi) + 0x8000u;
    unsigned b = __float_as_uint(lo) + 0x8000u;
    return __builtin_amdgcn_perm(a, b, 0x07060302u);
}
// pack 4 floats to 4 fp8 e4m3 bytes
__device__ __forceinline__ unsigned pack_fp8x4(float a, float b, float c, float d) {
    unsigned w = __builtin_amdgcn_cvt_pk_fp8_f32(a, b, 0, false);
    w = __builtin_amdgcn_cvt_pk_fp8_f32(c, d, w, true);
    return w;
}
__device__ __forceinline__ void async_copy16(const void* g, void* l) {
    __builtin_amdgcn_global_load_lds((__attribute__((address_space(1))) void*)(void*)g,
                                     (__attribute__((address_space(3))) void*)l, 16, 0, 0);
}

#define FP8_SCALE 64.0f          // pre-scale before e4m3 quant (avoids subnormals)
#define FP8_UNSCALE (1.0f / 4096.0f)  // (1/64)^2 applied at GEMM epilogue

// ---------------- prep kernels ----------------

__global__ void inv4_k(const int* __restrict__ q, const int* __restrict__ k,
                       const int* __restrict__ v, const int* __restrict__ o,
                       int* __restrict__ invq, int* __restrict__ invk,
                       int* __restrict__ invv, int* __restrict__ invo) {
    int i = blockIdx.x * 256 + threadIdx.x;   // grid 64 -> 16384 = 4*4096
    int a = i >> 12, j = i & 4095;
    const int* p = a == 0 ? q : a == 1 ? k : a == 2 ? v : o;
    int* inv = a == 0 ? invq : a == 1 ? invk : a == 2 ? invv : invo;
    inv[p[j]] = j;
}

// Weight permutations. Q,K rows -> fp8 (x64, XOR-swizzled 16B blocks); V,O rows -> bf16.
// Q,K additionally get a head-dim COLUMN permutation P (applied by selecting permuted
// weight rows) so RoPE pairs (d, d+64) land in adjacent j-fragments of one lane in the
// MFMA C-layout.  QK^T is invariant: Q and K share the same P.
//   P[hd] = (hd&15) | ((b&1)<<6) | ((b&2)<<3) | ((hd&64)>>1),  b = hd>>4
__global__ __launch_bounds__(256) void permw4_k(
    const float* __restrict__ Wq, const float* __restrict__ Wk,
    const float* __restrict__ Wv, const float* __restrict__ Wo,
    const int* __restrict__ qor, const int* __restrict__ kor,
    const int* __restrict__ vor, const int* __restrict__ oor,
    const int* __restrict__ invq, const int* __restrict__ invk,
    const int* __restrict__ invv, const int* __restrict__ invo,
    u8* __restrict__ Wqkf8, u16* __restrict__ Wvp, u16* __restrict__ Wop) {
    __shared__ float rowbuf[4096];
    int j = blockIdx.x;
    const float* W; const int* rp; const int* inv; int row; int f8;
    u8* out8 = nullptr; u16* out16 = nullptr;
    if (j < 4096)      { W = Wq; rp = qor; inv = invq; row = j;        out8 = Wqkf8 + (size_t)j * 4096; f8 = 1; }
    else if (j < 5120) { W = Wk; rp = kor; inv = invk; row = j - 4096; out8 = Wqkf8 + (size_t)j * 4096; f8 = 1; }
    else if (j < 6144) { W = Wv; rp = vor; inv = invv; row = j - 5120; out16 = Wvp + (size_t)(j - 5120) * 4096; f8 = 0; }
    else               { W = Wo; rp = oor; inv = invo; row = j - 6144; out16 = Wop + (size_t)(j - 6144) * 4096; f8 = 0; }
    if (f8) {   // head-dim column permutation for Q,K (RoPE pairing)
        int hd = row & 127, b = hd >> 4;
        row = (row & ~127) | ((hd & 15) | ((b & 1) << 6) | ((b & 2) << 3) | ((hd & 64) >> 1));
    }
    const float4* wr4 = (const float4*)(W + (size_t)rp[row] * 4096);
#pragma unroll
    for (int t = 0; t < 4; t++)
        ((float4*)rowbuf)[threadIdx.x + t * 256] = wr4[threadIdx.x + t * 256];
    __syncthreads();
    if (f8) {
        int t = threadIdx.x;                       // one 16B block per thread
        const int4* inv4p = (const int4*)inv;
        float v[16];
#pragma unroll
        for (int u = 0; u < 4; u++) {
            int4 ix = inv4p[t * 4 + u];
            v[4 * u + 0] = rowbuf[ix.x] * FP8_SCALE;
            v[4 * u + 1] = rowbuf[ix.y] * FP8_SCALE;
            v[4 * u + 2] = rowbuf[ix.z] * FP8_SCALE;
            v[4 * u + 3] = rowbuf[ix.w] * FP8_SCALE;
        }
        uint4 wv;
        wv.x = pack_fp8x4(v[0], v[1], v[2], v[3]);
        wv.y = pack_fp8x4(v[4], v[5], v[6], v[7]);
        wv.z = pack_fp8x4(v[8], v[9], v[10], v[11]);
        wv.w = pack_fp8x4(v[12], v[13], v[14], v[15]);
        int tb = (t & ~7) | ((t & 7) ^ (j & 7));   // XOR swizzle within 128B segment
        ((uint4*)out8)[tb] = wv;
    } else {
        unsigned* o32 = (unsigned*)out16;
        const int2* inv2 = (const int2*)inv;
#pragma unroll
        for (int t = 0; t < 8; t++) {
            int c = threadIdx.x + t * 256;
            int2 ij = inv2[c];
            o32[c] = pack_bf2(rowbuf[ij.x], rowbuf[ij.y]);
        }
    }
}

// hidden -> Xb (bf16) + Xf8 (fp8 x64, swizzled). One block per row of 4096.
__global__ __launch_bounds__(256) void cvt_k(const float* __restrict__ x,
                                             u16* __restrict__ Xb,
                                             u8* __restrict__ Xf8) {
    int row = blockIdx.x;
    int t = threadIdx.x;                           // 16 consecutive floats per thread
    const float4* src = (const float4*)(x + (size_t)row * 4096);
    float v[16];
#pragma unroll
    for (int u = 0; u < 4; u++) {
        float4 a = src[t * 4 + u];
        v[4 * u + 0] = a.x; v[4 * u + 1] = a.y; v[4 * u + 2] = a.z; v[4 * u + 3] = a.w;
    }
    uint4 b0, b1;
    b0.x = pack_bf2(v[0], v[1]);  b0.y = pack_bf2(v[2], v[3]);
    b0.z = pack_bf2(v[4], v[5]);  b0.w = pack_bf2(v[6], v[7]);
    b1.x = pack_bf2(v[8], v[9]);  b1.y = pack_bf2(v[10], v[11]);
    b1.z = pack_bf2(v[12], v[13]); b1.w = pack_bf2(v[14], v[15]);
    uint4* ob = (uint4*)(Xb + (size_t)row * 4096);
    ob[t * 2] = b0;
    ob[t * 2 + 1] = b1;
    uint4 w8;
    w8.x = pack_fp8x4(v[0] * FP8_SCALE, v[1] * FP8_SCALE, v[2] * FP8_SCALE, v[3] * FP8_SCALE);
    w8.y = pack_fp8x4(v[4] * FP8_SCALE, v[5] * FP8_SCALE, v[6] * FP8_SCALE, v[7] * FP8_SCALE);
    w8.z = pack_fp8x4(v[8] * FP8_SCALE, v[9] * FP8_SCALE, v[10] * FP8_SCALE, v[11] * FP8_SCALE);
    w8.w = pack_fp8x4(v[12] * FP8_SCALE, v[13] * FP8_SCALE, v[14] * FP8_SCALE, v[15] * FP8_SCALE);
    int tb = (t & ~7) | ((t & 7) ^ (row & 7));
    ((uint4*)(Xf8 + (size_t)row * 4096))[tb] = w8;
}

// V transpose (sums split-K fp32 partials, kappa-permuted cols). 512 blocks: 32 x 16.
__global__ __launch_bounds__(256) void vtr_k(const float* __restrict__ Vpart,
                                             u16* __restrict__ Vt) {
    __shared__ u16 t[64][65];
    int bx = blockIdx.x;
    int s0 = (bx & 31) * 64, c0 = (bx >> 5) * 64;
    int x = threadIdx.x & 63, y4 = threadIdx.x >> 6;
    const float* Vp0 = Vpart;
    const float* Vp1 = Vpart + (size_t)2048 * 1024;
    for (int i = 0; i < 16; i++) {
        int r = y4 * 16 + i;
        size_t idx = (size_t)(s0 + r) * 1024 + c0 + x;
        t[r][x] = f2bf(Vp0[idx] + Vp1[idx]);
    }
    __syncthreads();
    for (int i = 0; i < 16; i++) {
        int r = y4 * 16 + i;
        int xk = 4 * (x & 15) + (x >> 4);  // kappa permutation within 64-key tile
        Vt[(size_t)(c0 + r) * 2048 + s0 + xk] = t[x][r];
    }
}

// ---------------- merged QKV GEMM, depth-3 counted-vmcnt pipeline ----------------
// 512 threads, 8 waves as 2M x 4N (wave tile 64x32), LDS 3 x 32KB buffers (96 KB).
// blocks x<40: Q,K via MX-fp8 (128x128 tile, BK=128B, 32 tiles) + fused RoPE epilogue.
// blocks x in [40,56): V via bf16 (128x128 tile, BK=64, K-split2, 32 tiles), fp32 partials.
// 4 async_copy16/thread/tile -> steady-state vmcnt(8) (2 tiles in flight), peel 8->4->0.

#define QKV_BAR() asm volatile("s_barrier" ::: "memory")

#define QK_STAGE(bufi, kt) do {                                                   \
    u8* d_ = S8 + (bufi) * 32768 + tid * 16;                                      \
    const int k0_ = (kt) * 128;                                                   \
    async_copy16(AgQ + k0_, d_);                                                  \
    async_copy16(AgQ + (size_t)64 * 4096 + k0_, d_ + 8192);                       \
    async_copy16(BgQ + k0_, d_ + 16384);                                          \
    async_copy16(BgQ + (size_t)64 * 4096 + k0_, d_ + 24576);                      \
} while (0)

#define QK_COMPUTE(bufi) do {                                                     \
    const u8* la_ = S8 + (bufi) * 32768;                                          \
    const u8* lb_ = la_ + 16384;                                                  \
    i32x8 af0, af1, bf0, bf1;                                                     \
    union { i32x8 v8; i32x4 v4[2]; } u_;                                          \
    int R_ = (wn + l16) * 128;                                                    \
    u_.v4[0] = *(const i32x4*)&lb_[R_ + s0b];                                     \
    u_.v4[1] = *(const i32x4*)&lb_[R_ + s1b]; bf0 = u_.v8;                        \
    R_ = (wn + 16 + l16) * 128;                                                   \
    u_.v4[0] = *(const i32x4*)&lb_[R_ + s0b];                                     \
    u_.v4[1] = *(const i32x4*)&lb_[R_ + s1b]; bf1 = u_.v8;                        \
    R_ = (wm + l16) * 128;                                                        \
    u_.v4[0] = *(const i32x4*)&la_[R_ + s0b];                                     \
    u_.v4[1] = *(const i32x4*)&la_[R_ + s1b]; af0 = u_.v8;                        \
    R_ = (wm + 16 + l16) * 128;                                                   \
    u_.v4[0] = *(const i32x4*)&la_[R_ + s0b];                                     \
    u_.v4[1] = *(const i32x4*)&la_[R_ + s1b]; af1 = u_.v8;                        \
    asm volatile("s_waitcnt lgkmcnt(0)" ::: "memory");                            \
    __builtin_amdgcn_sched_barrier(0);                                            \
    __builtin_amdgcn_s_setprio(1);                                                \
    acc[0][0] = __builtin_amdgcn_mfma_scale_f32_16x16x128_f8f6f4(af0, bf0, acc[0][0], 0, 0, 0, 0x7F7F7F7F, 0, 0x7F7F7F7F); \
    acc[0][1] = __builtin_amdgcn_mfma_scale_f32_16x16x128_f8f6f4(af0, bf1, acc[0][1], 0, 0, 0, 0x7F7F7F7F, 0, 0x7F7F7F7F); \
    acc[1][0] = __builtin_amdgcn_mfma_scale_f32_16x16x128_f8f6f4(af1, bf0, acc[1][0], 0, 0, 0, 0x7F7F7F7F, 0, 0x7F7F7F7F); \
    acc[1][1] = __builtin_amdgcn_mfma_scale_f32_16x16x128_f8f6f4(af1, bf1, acc[1][1], 0, 0, 0, 0x7F7F7F7F, 0, 0x7F7F7F7F); \
    __builtin_amdgcn_s_setprio(0);                                                \
    R_ = (wm + 32 + l16) * 128;                                                   \
    u_.v4[0] = *(const i32x4*)&la_[R_ + s0b];                                     \
    u_.v4[1] = *(const i32x4*)&la_[R_ + s1b]; af0 = u_.v8;                        \
    R_ = (wm + 48 + l16) * 128;                                                   \
    u_.v4[0] = *(const i32x4*)&la_[R_ + s0b];                                     \
    u_.v4[1] = *(const i32x4*)&la_[R_ + s1b]; af1 = u_.v8;                        \
    asm volatile("s_waitcnt lgkmcnt(0)" ::: "memory");                            \
    __builtin_amdgcn_sched_barrier(0);                                            \
    __builtin_amdgcn_s_setprio(1);                                                \
    acc[2][0] = __builtin_amdgcn_mfma_scale_f32_16x16x128_f8f6f4(af0, bf0, acc[2][0], 0, 0, 0, 0x7F7F7F7F, 0, 0x7F7F7F7F); \
    acc[2][1] = __builtin_amdgcn_mfma_scale_f32_16x16x128_f8f6f4(af0, bf1, acc[2][1], 0, 0, 0, 0x7F7F7F7F, 0, 0x7F7F7F7F); \
    acc[3][0] = __builtin_amdgcn_mfma_scale_f32_16x16x128_f8f6f4(af1, bf0, acc[3][0], 0, 0, 0, 0x7F7F7F7F, 0, 0x7F7F7F7F); \
    acc[3][1] = __builtin_amdgcn_mfma_scale_f32_16x16x128_f8f6f4(af1, bf1, acc[3][1], 0, 0, 0, 0x7F7F7F7F, 0, 0x7F7F7F7F); \
    __builtin_amdgcn_s_setprio(0);                                                \
} while (0)

#define V_STAGE(bufi, kt) do {                                                    \
    u8* d_ = S8 + (bufi) * 32768 + tid * 16;                                      \
    const int k0_ = (kt) * 64;                                                    \
    async_copy16(AgV + k0_, d_);                                                  \
    async_copy16(AgV + (size_t)64 * 4096 + k0_, d_ + 8192);                       \
    async_copy16(BgV + k0_, d_ + 16384);                                          \
    async_copy16(BgV + (size_t)64 * 4096 + k0_, d_ + 24576);                      \
} while (0)

#define V_COMPUTE(bufi) do {                                                      \
    const u16* la_ = (const u16*)(S8 + (bufi) * 32768);                           \
    const u16* lb_ = la_ + 8192;                                                  \
    _Pragma("unroll")                                                             \
    for (int kk_ = 0; kk_ < 2; kk_++) {                                           \
        const int so_ = ((kk_ * 4 + quad) ^ swz) * 8;                             \
        bf16x8 bv0 = *(const bf16x8*)&lb_[(wn + l16) * 64 + so_];                 \
        bf16x8 bv1 = *(const bf16x8*)&lb_[(wn + 16 + l16) * 64 + so_];            \
        bf16x8 a0 = *(const bf16x8*)&la_[(wm + l16) * 64 + so_];                  \
        bf16x8 a1 = *(const bf16x8*)&la_[(wm + 16 + l16) * 64 + so_];             \
        bf16x8 a2 = *(const bf16x8*)&la_[(wm + 32 + l16) * 64 + so_];             \
        bf16x8 a3 = *(const bf16x8*)&la_[(wm + 48 + l16) * 64 + so_];             \
        asm volatile("s_waitcnt lgkmcnt(0)" ::: "memory");                        \
        __builtin_amdgcn_sched_barrier(0);                                        \
        __builtin_amdgcn_s_setprio(1);                                            \
        acc[0][0] = __builtin_amdgcn_mfma_f32_16x16x32_bf16(a0, bv0, acc[0][0], 0, 0, 0); \
        acc[0][1] = __builtin_amdgcn_mfma_f32_16x16x32_bf16(a0, bv1, acc[0][1], 0, 0, 0); \
        acc[1][0] = __builtin_amdgcn_mfma_f32_16x16x32_bf16(a1, bv0, acc[1][0], 0, 0, 0); \
        acc[1][1] = __builtin_amdgcn_mfma_f32_16x16x32_bf16(a1, bv1, acc[1][1], 0, 0, 0); \
        acc[2][0] = __builtin_amdgcn_mfma_f32_16x16x32_bf16(a2, bv0, acc[2][0], 0, 0, 0); \
        acc[2][1] = __builtin_amdgcn_mfma_f32_16x16x32_bf16(a2, bv1, acc[2][1], 0, 0, 0); \
        acc[3][0] = __builtin_amdgcn_mfma_f32_16x16x32_bf16(a3, bv0, acc[3][0], 0, 0, 0); \
        acc[3][1] = __builtin_amdgcn_mfma_f32_16x16x32_bf16(a3, bv1, acc[3][1], 0, 0, 0); \
        __builtin_amdgcn_s_setprio(0);                                            \
    }                                                                             \
} while (0)

__global__ __launch_bounds__(512, 2) void gemm_qkv_k(const u8* __restrict__ Xf8,
                                                     const u16* __restrict__ Xb,
                                                     const u8* __restrict__ Wqk,
                                                     const u16* __restrict__ Wv,
                                                     u16* __restrict__ QKV,
                                                     float* __restrict__ Vpart,
                                                     const float* __restrict__ cosv,
                                                     const float* __restrict__ sinv) {
    extern __shared__ u8 S8[];                 // 3 * 32768 = 96 KB
    const int tid = threadIdx.x;
    const int w = tid >> 6, lane = tid & 63;
    const int quad = lane >> 4, l16 = lane & 15;
    const int bm0 = blockIdx.y * 128;
    const int wm = (w >> 2) * 64;              // 2 waves along M
    const int wn = (w & 3) * 32;               // 4 waves along N
    const int swz = l16 & 7;                   // fragment row & 7
    const int s0b = ((quad * 2) ^ swz) * 16;   // fp8 16B-slot byte offsets
    const int s1b = ((quad * 2 + 1) ^ swz) * 16;

    if (blockIdx.x < 40) {
        // ---------------- Q,K MX-fp8 path ----------------
        const int bn0 = blockIdx.x * 128;
        // staging: thread covers rows (tid>>3) and 64+(tid>>3); global is pre-swizzled
        const u8* AgQ = Xf8 + (size_t)(bm0 + (tid >> 3)) * 4096 + (tid & 7) * 16;
        const u8* BgQ = Wqk + (size_t)(bn0 + (tid >> 3)) * 4096 + (tid & 7) * 16;
        f32x4 acc[4][2] = {};

        QK_STAGE(0, 0);
        QK_STAGE(1, 1);
        QK_STAGE(2, 2);
        asm volatile("s_waitcnt vmcnt(8)" ::: "memory");
        QKV_BAR();
        int cur = 0;
        for (int t = 0; t < 29; ++t) {
            QK_COMPUTE(cur);
            QKV_BAR();
            QK_STAGE(cur, t + 3);
            asm volatile("s_waitcnt vmcnt(8)" ::: "memory");
            QKV_BAR();
            cur = (cur == 2) ? 0 : cur + 1;
        }
        QK_COMPUTE(2);
        asm volatile("s_waitcnt vmcnt(4)" ::: "memory");
        QKV_BAR();
        QK_COMPUTE(0);
        asm volatile("s_waitcnt vmcnt(0)" ::: "memory");
        QKV_BAR();
        QK_COMPUTE(1);

        // fused RoPE epilogue: cols (c, c+16) of this wave hold logical dims (d1, d1+64)
        const float qsc = (bn0 < 4096) ? 0.08838834764831845f : 1.0f;  // 1/sqrt(128) for Q
        const int d1 = (w & 3) * 16 + l16;
        const int col0 = bn0 + wn + l16;
#pragma unroll
        for (int i = 0; i < 4; i++) {
            const int row = bm0 + wm + i * 16 + quad * 4;
#pragma unroll
            for (int r = 0; r < 4; r++) {
                const int s = row + r;
                const float c  = cosv[s * 128 + d1];
                const float sn = sinv[s * 128 + d1];
                const float x1 = acc[i][0][r] * FP8_UNSCALE;
                const float x2 = acc[i][1][r] * FP8_UNSCALE;
                QKV[(size_t)s * 6144 + col0]      = f2bf((x1 * c - x2 * sn) * qsc);
                QKV[(size_t)s * 6144 + col0 + 16] = f2bf((x2 * c + x1 * sn) * qsc);
            }
        }
    } else {
        // ---------------- V bf16 path (2-way split-K) ----------------
        const int vx = blockIdx.x - 40;        // 16 slots: 8 n-tiles x 2 k-slices
        const int bn0 = (vx & 7) * 128;
        const int kslice = vx >> 3;
        const int kb = kslice * 2048;
        // staging with inverse-swizzled global source (linear LDS dest)
        const int srow = tid >> 3;
        const int sblk = (tid & 7) ^ (srow & 7);
        const u16* AgV = Xb + (size_t)(bm0 + srow) * 4096 + kb + sblk * 8;
        const u16* BgV = Wv + (size_t)(bn0 + srow) * 4096 + kb + sblk * 8;
        f32x4 acc[4][2] = {};

        V_STAGE(0, 0);
        V_STAGE(1, 1);
        V_STAGE(2, 2);
        asm volatile("s_waitcnt vmcnt(8)" ::: "memory");
        QKV_BAR();
        int cur = 0;
        for (int t = 0; t < 29; ++t) {
            V_COMPUTE(cur);
            QKV_BAR();
            V_STAGE(cur, t + 3);
            asm volatile("s_waitcnt vmcnt(8)" ::: "memory");
            QKV_BAR();
            cur = (cur == 2) ? 0 : cur + 1;
        }
        V_COMPUTE(2);
        asm volatile("s_waitcnt vmcnt(4)" ::: "memory");
        QKV_BAR();
        V_COMPUTE(0);
        asm volatile("s_waitcnt vmcnt(0)" ::: "memory");
        QKV_BAR();
        V_COMPUTE(1);

        float* Vp = Vpart + (size_t)kslice * 2048 * 1024;
#pragma unroll
        for (int i = 0; i < 4; i++) {
            const int row = bm0 + wm + i * 16 + quad * 4;
#pragma unroll
            for (int j = 0; j < 2; j++) {
                const int col = bn0 + wn + j * 16 + l16;
#pragma unroll
                for (int r = 0; r < 4; r++)
                    Vp[(size_t)(row + r) * 1024 + col] = acc[i][j][r];
            }
        }
    }
}

// ---------------- O-projection GEMM: single-pass K=4096, depth-3 counted-vmcnt pipeline --------
// BM=256, BN=128, BK=64. 512 thr (8 waves, 4Mx2N, 64x64/wave). LDS: 3 x 48KB buffers (dynamic).
// Stage uses inverse-swizzled global source (linear LDS dest); ds_read applies slot^=(row&7)
// -> conflict-free b128 batches. vmcnt(12) steady state (2 tiles in flight), peel 12->6->0.
// Direct fp32 store to d_out: no split-K, no atomics, no memset, no reduce.

#define GO_STAGE(bufi, kt) do {                                                   \
    u16* la_ = S + (bufi) * 24576;                                                \
    u16* lb_ = la_ + 16384;                                                       \
    const int k0_ = (kt) * 64;                                                    \
    _Pragma("unroll")                                                             \
    for (int u = 0; u < 4; u++)                                                   \
        async_copy16(Asrc + (size_t)u * 64 * 4096 + k0_, la_ + u * 4096 + sdst);  \
    _Pragma("unroll")                                                             \
    for (int u = 0; u < 2; u++)                                                   \
        async_copy16(Bsrc + (size_t)u * 64 * 4096 + k0_, lb_ + u * 4096 + sdst);  \
} while (0)

#define GO_COMPUTE(bufi) do {                                                     \
    const u16* la_ = S + (bufi) * 24576;                                          \
    const u16* lb_ = la_ + 16384;                                                 \
    bf16x8 bfr[4][2], afr[2][2];                                                  \
    _Pragma("unroll")                                                             \
    for (int j = 0; j < 4; j++) {                                                 \
        const int rb_ = (wn + j * 16 + l16) * 64;                                 \
        bfr[j][0] = *(const bf16x8*)&lb_[rb_ + o0];                               \
        bfr[j][1] = *(const bf16x8*)&lb_[rb_ + o1];                               \
    }                                                                             \
    _Pragma("unroll")                                                             \
    for (int i = 0; i < 2; i++) {                                                 \
        const int ra_ = (wm + i * 16 + l16) * 64;                                 \
        afr[i][0] = *(const bf16x8*)&la_[ra_ + o0];                               \
        afr[i][1] = *(const bf16x8*)&la_[ra_ + o1];                               \
    }                                                                             \
    asm volatile("s_waitcnt lgkmcnt(0)" ::: "memory");                            \
    __builtin_amdgcn_sched_barrier(0);                                            \
    __builtin_amdgcn_s_setprio(1);                                                \
    _Pragma("unroll")                                                             \
    for (int i = 0; i < 2; i++)                                                   \
        _Pragma("unroll")                                                         \
        for (int j = 0; j < 4; j++) {                                             \
            acc[i][j] = __builtin_amdgcn_mfma_f32_16x16x32_bf16(afr[i][0], bfr[j][0], acc[i][j], 0, 0, 0); \
            acc[i][j] = __builtin_amdgcn_mfma_f32_16x16x32_bf16(afr[i][1], bfr[j][1], acc[i][j], 0, 0, 0); \
        }                                                                         \
    __builtin_amdgcn_s_setprio(0);                                                \
    _Pragma("unroll")                                                             \
    for (int i = 0; i < 2; i++) {                                                 \
        const int ra_ = (wm + (i + 2) * 16 + l16) * 64;                           \
        afr[i][0] = *(const bf16x8*)&la_[ra_ + o0];                               \
        afr[i][1] = *(const bf16x8*)&la_[ra_ + o1];                               \
    }                                                                             \
    asm volatile("s_waitcnt lgkmcnt(0)" ::: "memory");                            \
    __builtin_amdgcn_sched_barrier(0);                                            \
    __builtin_amdgcn_s_setprio(1);                                                \
    _Pragma("unroll")                                                             \
    for (int i = 0; i < 2; i++)                                                   \
        _Pragma("unroll")                                                         \
        for (int j = 0; j < 4; j++) {                                             \
            acc[i + 2][j] = __builtin_amdgcn_mfma_f32_16x16x32_bf16(afr[i][0], bfr[j][0], acc[i + 2][j], 0, 0, 0); \
            acc[i + 2][j] = __builtin_amdgcn_mfma_f32_16x16x32_bf16(afr[i][1], bfr[j][1], acc[i + 2][j], 0, 0, 0); \
        }                                                                         \
    __builtin_amdgcn_s_setprio(0);                                                \
} while (0)

#define GO_BAR() asm volatile("s_barrier" ::: "memory")

__global__ __launch_bounds__(512, 2) void gemm_o_k(const u16* __restrict__ A,
                                                   const u16* __restrict__ B,
                                                   float* __restrict__ Out) {
    extern __shared__ u16 S[];                 // 3 * 49152 B = 144 KB
    const int tid = threadIdx.x;
    const int w = tid >> 6, lane = tid & 63;
    const int quad = lane >> 4, l16 = lane & 15;
    // XCD-bijective swizzle over 256 blocks: each XCD gets one contiguous m-row (A-panel L2-resident)
    const int linear = blockIdx.y * 32 + blockIdx.x;
    const int wgid = (linear & 7) * 32 + (linear >> 3);
    const int bm0 = (wgid >> 5) * 256;
    const int bn0 = (wgid & 31) * 128;
    const int wm = (w >> 1) * 64;              // 4 waves along M
    const int wn = (w & 1) * 64;               // 2 waves along N
    // staging: thread -> (row = u*64 + tid>>3, col16B = (tid&7) ^ (row&7))  [inverse swizzle]
    const int sr = tid >> 3;
    const int scg = ((tid & 7) ^ (sr & 7)) * 8;
    const int sdst = tid * 8;                  // u16 units (16B/thread)
    const u16* Asrc = A + (size_t)(bm0 + sr) * 4096 + scg;
    const u16* Bsrc = B + (size_t)(bn0 + sr) * 4096 + scg;
    // fragment read swizzle: slot = ((kk<<2)|quad) ^ (row&7); row&7 == l16&7 here
    const int swz = l16 & 7;
    const int o0 = (quad ^ swz) * 8;           // u16 offset for kk=0
    const int o1 = ((4 | quad) ^ swz) * 8;     // u16 offset for kk=1

    f32x4 acc[4][4] = {};

    GO_STAGE(0, 0);
    GO_STAGE(1, 1);
    GO_STAGE(2, 2);
    asm volatile("s_waitcnt vmcnt(12)" ::: "memory");   // tile 0 landed
    GO_BAR();

    int cur = 0;
    for (int t = 0; t < 61; ++t) {
        GO_COMPUTE(cur);
        GO_BAR();                                        // all waves done reading buf[cur]
        GO_STAGE(cur, t + 3);
        asm volatile("s_waitcnt vmcnt(12)" ::: "memory"); // tile t+1 landed (t+2,t+3 in flight)
        GO_BAR();
        cur = (cur == 2) ? 0 : cur + 1;
    }
    // t = 61 (buf 1): tile 63's 6 loads may still be in flight
    GO_COMPUTE(1);
    asm volatile("s_waitcnt vmcnt(6)" ::: "memory");      // tile 62 landed
    GO_BAR();
    // t = 62 (buf 2)
    GO_COMPUTE(2);
    asm volatile("s_waitcnt vmcnt(0)" ::: "memory");      // tile 63 landed
    GO_BAR();
    // t = 63 (buf 0)
    GO_COMPUTE(0);

#pragma unroll
    for (int i = 0; i < 4; i++) {
        const int row = bm0 + wm + i * 16 + quad * 4;
#pragma unroll
        for (int j = 0; j < 4; j++) {
            const int col = bn0 + wn + j * 16 + l16;
#pragma unroll
            for (int r = 0; r < 4; r++)
                Out[(size_t)(row + r) * 4096 + col] = acc[i][j][r];
        }
    }
}

// ---------------- fused flash attention (GQA, causal, no-max softmax) ----------------

__global__ __launch_bounds__(256) void attn_k(const u16* __restrict__ Qb,
                                              const u16* __restrict__ Kb,
                                              const u16* __restrict__ Vt,
                                              u16* __restrict__ Ob,
                                              int qstride, int kstride) {
    __shared__ u16 ldsK[4 * 64 * 32];   // [kk][key][hd32]
    __shared__ u16 ldsV[2 * 128 * 32];  // [ks][d][kappa32]
    __shared__ u16 ldsP[4][32 * 72];    // per-wave [m 32][kappa 64 + pad 8]
    const int h = blockIdx.x;
    const int qt = (int)gridDim.y - 1 - (int)blockIdx.y;  // heavy tiles first
    const int kvh = h >> 2;
    const int tid = threadIdx.x;
    const int w = tid >> 6, lane = tid & 63;
    const int quad = lane >> 4, l16 = lane & 15;
    const int q0 = qt * 128;
    const int wrow = q0 + w * 32;

    bf16x8 qf[2][4];
#pragma unroll
    for (int mi = 0; mi < 2; mi++)
#pragma unroll
        for (int kk = 0; kk < 4; kk++)
            qf[mi][kk] = *(const bf16x8*)&Qb[(size_t)(wrow + mi * 16 + l16) * qstride +
                                             h * 128 + kk * 32 + quad * 8];

    const u16* kp[4]; const u16* vp[4];
    u16* ldk[4]; u16* ldv[4];
#pragma unroll
    for (int t = 0; t < 4; t++) {
        int wl = w + t * 4;
        int kk = wl >> 2, part = wl & 3;
        kp[t] = Kb + (size_t)(part * 16 + (lane >> 2)) * kstride + kvh * 128 + kk * 32 + (lane & 3) * 8;
        int ks2 = wl >> 3, p2 = wl & 7;
        vp[t] = Vt + (size_t)(kvh * 128 + p2 * 16 + (lane >> 2)) * 2048 + ks2 * 32 + (lane & 3) * 8;
        ldk[t] = ldsK + wl * 512;
        ldv[t] = ldsV + wl * 512;
    }

    f32x4 acc_o[2][8] = {};
    float lrow[2][4] = {};

    const int nk = 2 * (qt + 1);
    for (int kn = 0; kn < nk; kn++) {
        const int g0 = kn * 64;
#pragma unroll
        for (int t = 0; t < 4; t++) async_copy16(kp[t], ldk[t]);
#pragma unroll
        for (int t = 0; t < 4; t++) async_copy16(vp[t], ldv[t]);
#pragma unroll
        for (int t = 0; t < 4; t++) { kp[t] += (size_t)64 * kstride; vp[t] += 64; }
        __syncthreads();

        if (g0 <= wrow + 31) {
            f32x4 accs[2][4] = {};
#pragma unroll
            for (int kk = 0; kk < 4; kk++) {
                bf16x8 bfrag[4];
#pragma unroll
                for (int ni = 0; ni < 4; ni++)
                    bfrag[ni] = *(const bf16x8*)&ldsK[kk * 2048 + (ni * 16 + l16) * 32 + quad * 8];
#pragma unroll
                for (int mi = 0; mi < 2; mi++)
#pragma unroll
                    for (int ni = 0; ni < 4; ni++)
                        accs[mi][ni] = __builtin_amdgcn_mfma_f32_16x16x32_bf16(
                            qf[mi][kk], bfrag[ni], accs[mi][ni], 0, 0, 0);
            }
            const bool diag = (g0 + 63 > wrow);
            int kidx[4];
#pragma unroll
            for (int ni = 0; ni < 4; ni++) kidx[ni] = g0 + ni * 16 + l16;
#pragma unroll
            for (int mi = 0; mi < 2; mi++) {
#pragma unroll
                for (int r = 0; r < 4; r++) {
                    const int qrow = wrow + mi * 16 + quad * 4 + r;
                    float p[4];
#pragma unroll
                    for (int ni = 0; ni < 4; ni++) {
                        float s = accs[mi][ni][r];
                        if (diag && (kidx[ni] > qrow)) s = -1e30f;
                        p[ni] = __expf(s);
                    }
                    lrow[mi][r] += (p[0] + p[1]) + (p[2] + p[3]);
                    uint2 pk;
                    pk.x = pack_bf2(p[0], p[1]);
                    pk.y = pack_bf2(p[2], p[3]);
                    *(uint2*)&ldsP[w][(mi * 16 + quad * 4 + r) * 72 + l16 * 4] = pk;
                }
            }
#pragma unroll
            for (int ks = 0; ks < 2; ks++) {
                bf16x8 pa[2];
#pragma unroll
                for (int mi = 0; mi < 2; mi++)
                    pa[mi] = *(const bf16x8*)&ldsP[w][(mi * 16 + l16) * 72 + ks * 32 + quad * 8];
#pragma unroll
                for (int oj = 0; oj < 8; oj++) {
                    bf16x8 vb = *(const bf16x8*)&ldsV[ks * 4096 + (oj * 16 + l16) * 32 + quad * 8];
#pragma unroll
                    for (int mi = 0; mi < 2; mi++)
                        acc_o[mi][oj] = __builtin_amdgcn_mfma_f32_16x16x32_bf16(
                            pa[mi], vb, acc_o[mi][oj], 0, 0, 0);
                }
            }
        }
        __syncthreads();
    }
#pragma unroll
    for (int mi = 0; mi < 2; mi++)
#pragma unroll
        for (int r = 0; r < 4; r++) {
            float l = lrow[mi][r];
            l += __shfl_xor(l, 1);
            l += __shfl_xor(l, 2);
            l += __shfl_xor(l, 4);
            l += __shfl_xor(l, 8);
            const float inv = 1.0f / l;
            const int qrow = wrow + mi * 16 + quad * 4 + r;
#pragma unroll
            for (int oj = 0; oj < 8; oj++)
                Ob[(size_t)qrow * 4096 + h * 128 + oj * 16 + l16] =
                    f2bf(acc_o[mi][oj][r] * inv);
        }
}

// ---------------- launch ----------------

extern "C" void kernel_launch(void* const* d_in, const int* in_sizes, int n_in,
                              void* d_out, int out_size, void* d_ws, size_t ws_size,
                              hipStream_t stream) {
    (void)in_sizes; (void)n_in; (void)out_size; (void)ws_size;
    const float* hidden = (const float*)d_in[0];
    const float* Wq = (const float*)d_in[1];
    const float* Wk = (const float*)d_in[2];
    const float* Wv = (const float*)d_in[3];
    const float* Wo = (const float*)d_in[4];
    const float* cosv = (const float*)d_in[5];
    const float* sinv = (const float*)d_in[6];
    const int* qoc = (const int*)d_in[8];
    const int* qor = (const int*)d_in[9];
    const int* koc = (const int*)d_in[10];
    const int* kor = (const int*)d_in[11];
    const int* voc = (const int*)d_in[12];
    const int* vor = (const int*)d_in[13];
    const int* ooc = (const int*)d_in[14];
    const int* oor = (const int*)d_in[15];

    char* ws = (char*)d_ws;
    size_t off = 0;
    // persistent across the whole pipeline:
    int* invq = (int*)(ws + off); off += 16384;
    int* invk = (int*)(ws + off); off += 16384;
    int* invv = (int*)(ws + off); off += 16384;
    int* invo = (int*)(ws + off); off += 16384;
    u16* Wop   = (u16*)(ws + off); off += (size_t)4096 * 4096 * 2;   // 33.5 MB (live at O-proj)
    u16* Xb    = (u16*)(ws + off); off += (size_t)2048 * 4096 * 2;   // 16.8 MB (live as Attb)
    u8*  Wqkf8 = (u8*)(ws + off);  off += (size_t)5120 * 4096;       // 21.0 MB
    u16* Wvp   = (u16*)(ws + off); off += (size_t)1024 * 4096 * 2;   //  8.4 MB
    u8*  Xf8   = (u8*)(ws + off);  off += (size_t)2048 * 4096;       //  8.4 MB
    u16* QKVb  = (u16*)(ws + off); off += (size_t)2048 * 6144 * 2;   // 25.2 MB
    u16* Vtb   = (u16*)(ws + off); off += (size_t)1024 * 2048 * 2;   //  4.2 MB
    float* Vpart = (float*)(ws + off); off += (size_t)2 * 2048 * 1024 * 4;  // 16.8 MB
    u16* Attb  = Xb;   // Xb dead after gemm_qkv_k; reuse for attention output

    inv4_k<<<64, 256, 0, stream>>>(qoc, koc, voc, ooc, invq, invk, invv, invo);
    permw4_k<<<10240, 256, 0, stream>>>(Wq, Wk, Wv, Wo, qor, kor, vor, oor,
                                        invq, invk, invv, invo, Wqkf8, Wvp, Wop);
    cvt_k<<<2048, 256, 0, stream>>>(hidden, Xb, Xf8);

    // QKV: Q,K via MX-fp8 (+fused RoPE/scale) + V via bf16 split-K2 -> QKVb + Vpart
    gemm_qkv_k<<<dim3(56, 16), 512, 98304, stream>>>(Xf8, Xb, Wqkf8, Wvp, QKVb, Vpart,
                                                     cosv, sinv);

    // Vt build (sums split-K partials, kappa permutation)
    vtr_k<<<512, 256, 0, stream>>>(Vpart, Vtb);

    // attention -> Attb [2048][4096]  (reuses Xb storage)
    attn_k<<<dim3(32, 16), 256, 0, stream>>>(QKVb, QKVb + 4096, Vtb, Attb, 6144, 6144);

    // O-projection: single-pass pipelined bf16 GEMM, direct fp32 store
    gemm_o_k<<<dim3(32, 8), 512, 147456, stream>>>(Attb, Wop, (float*)d_out);
}

// Round 4
// 471.707 us; speedup vs baseline: 1.0557x; 1.0557x over previous
//
#include <hip/hip_runtime.h>

typedef unsigned short u16;
typedef unsigned char u8;
typedef __bf16 bf16x8 __attribute__((ext_vector_type(8)));
typedef float f32x4 __attribute__((ext_vector_type(4)));
typedef int i32x4 __attribute__((ext_vector_type(4)));
typedef int i32x8 __attribute__((ext_vector_type(8)));

__device__ __forceinline__ u16 f2bf(float f) {
    unsigned u = __float_as_uint(f);
    unsigned r = (u + 0x7fffu + ((u >> 16) & 1u)) >> 16;
    return (u16)r;
}
__device__ __forceinline__ float bf2f(u16 h) {
    return __uint_as_float(((unsigned)h) << 16);
}
// pack two floats to bf16x2 (lo in low half), round-half-up, single v_perm
__device__ __forceinline__ unsigned pack_bf2(float lo, float hi) {
    unsigned a = __float_as_uint(hi) + 0x8000u;
    unsigned b = __float_as_uint(lo) + 0x8000u;
    return __builtin_amdgcn_perm(a, b, 0x07060302u);
}
// pack 4 floats to 4 fp8 e4m3 bytes
__device__ __forceinline__ unsigned pack_fp8x4(float a, float b, float c, float d) {
    unsigned w = __builtin_amdgcn_cvt_pk_fp8_f32(a, b, 0, false);
    w = __builtin_amdgcn_cvt_pk_fp8_f32(c, d, w, true);
    return w;
}
__device__ __forceinline__ void async_copy16(const void* g, void* l) {
    __builtin_amdgcn_global_load_lds((__attribute__((address_space(1))) void*)(void*)g,
                                     (__attribute__((address_space(3))) void*)l, 16, 0, 0);
}

#define FP8_SCALE 64.0f          // pre-scale before e4m3 quant (avoids subnormals)
#define FP8_UNSCALE (1.0f / 4096.0f)  // (1/64)^2 applied at GEMM epilogue

// ---------------- prep kernels ----------------

__global__ void inv4_k(const int* __restrict__ q, const int* __restrict__ k,
                       const int* __restrict__ v, const int* __restrict__ o,
                       int* __restrict__ invq, int* __restrict__ invk,
                       int* __restrict__ invv, int* __restrict__ invo) {
    int i = blockIdx.x * 256 + threadIdx.x;   // grid 64 -> 16384 = 4*4096
    int a = i >> 12, j = i & 4095;
    const int* p = a == 0 ? q : a == 1 ? k : a == 2 ? v : o;
    int* inv = a == 0 ? invq : a == 1 ? invk : a == 2 ? invv : invo;
    inv[p[j]] = j;
}

// Weight permutations. Q,K rows -> fp8 (x64, XOR-swizzled 16B blocks); V,O rows -> bf16.
// Q,K additionally get a head-dim COLUMN permutation P (applied by selecting permuted
// weight rows) so RoPE pairs (d, d+64) land in adjacent j-fragments of one lane in the
// MFMA C-layout.  QK^T is invariant: Q and K share the same P.
//   P[hd] = (hd&15) | ((b&1)<<6) | ((b&2)<<3) | ((hd&64)>>1),  b = hd>>4
__global__ __launch_bounds__(256) void permw4_k(
    const float* __restrict__ Wq, const float* __restrict__ Wk,
    const float* __restrict__ Wv, const float* __restrict__ Wo,
    const int* __restrict__ qor, const int* __restrict__ kor,
    const int* __restrict__ vor, const int* __restrict__ oor,
    const int* __restrict__ invq, const int* __restrict__ invk,
    const int* __restrict__ invv, const int* __restrict__ invo,
    u8* __restrict__ Wqkf8, u16* __restrict__ Wvp, u16* __restrict__ Wop) {
    __shared__ float rowbuf[4096];
    int j = blockIdx.x;
    const float* W; const int* rp; const int* inv; int row; int f8;
    u8* out8 = nullptr; u16* out16 = nullptr;
    if (j < 4096)      { W = Wq; rp = qor; inv = invq; row = j;        out8 = Wqkf8 + (size_t)j * 4096; f8 = 1; }
    else if (j < 5120) { W = Wk; rp = kor; inv = invk; row = j - 4096; out8 = Wqkf8 + (size_t)j * 4096; f8 = 1; }
    else if (j < 6144) { W = Wv; rp = vor; inv = invv; row = j - 5120; out16 = Wvp + (size_t)(j - 5120) * 4096; f8 = 0; }
    else               { W = Wo; rp = oor; inv = invo; row = j - 6144; out16 = Wop + (size_t)(j - 6144) * 4096; f8 = 0; }
    if (f8) {   // head-dim column permutation for Q,K (RoPE pairing)
        int hd = row & 127, b = hd >> 4;
        row = (row & ~127) | ((hd & 15) | ((b & 1) << 6) | ((b & 2) << 3) | ((hd & 64) >> 1));
    }
    const float4* wr4 = (const float4*)(W + (size_t)rp[row] * 4096);
#pragma unroll
    for (int t = 0; t < 4; t++)
        ((float4*)rowbuf)[threadIdx.x + t * 256] = wr4[threadIdx.x + t * 256];
    __syncthreads();
    if (f8) {
        int t = threadIdx.x;                       // one 16B block per thread
        const int4* inv4p = (const int4*)inv;
        float v[16];
#pragma unroll
        for (int u = 0; u < 4; u++) {
            int4 ix = inv4p[t * 4 + u];
            v[4 * u + 0] = rowbuf[ix.x] * FP8_SCALE;
            v[4 * u + 1] = rowbuf[ix.y] * FP8_SCALE;
            v[4 * u + 2] = rowbuf[ix.z] * FP8_SCALE;
            v[4 * u + 3] = rowbuf[ix.w] * FP8_SCALE;
        }
        uint4 wv;
        wv.x = pack_fp8x4(v[0], v[1], v[2], v[3]);
        wv.y = pack_fp8x4(v[4], v[5], v[6], v[7]);
        wv.z = pack_fp8x4(v[8], v[9], v[10], v[11]);
        wv.w = pack_fp8x4(v[12], v[13], v[14], v[15]);
        int tb = (t & ~7) | ((t & 7) ^ (j & 7));   // XOR swizzle within 128B segment
        ((uint4*)out8)[tb] = wv;
    } else {
        unsigned* o32 = (unsigned*)out16;
        const int2* inv2 = (const int2*)inv;
#pragma unroll
        for (int t = 0; t < 8; t++) {
            int c = threadIdx.x + t * 256;
            int2 ij = inv2[c];
            o32[c] = pack_bf2(rowbuf[ij.x], rowbuf[ij.y]);
        }
    }
}

// hidden -> Xb (bf16) + Xf8 (fp8 x64, swizzled). One block per row of 4096.
__global__ __launch_bounds__(256) void cvt_k(const float* __restrict__ x,
                                             u16* __restrict__ Xb,
                                             u8* __restrict__ Xf8) {
    int row = blockIdx.x;
    int t = threadIdx.x;                           // 16 consecutive floats per thread
    const float4* src = (const float4*)(x + (size_t)row * 4096);
    float v[16];
#pragma unroll
    for (int u = 0; u < 4; u++) {
        float4 a = src[t * 4 + u];
        v[4 * u + 0] = a.x; v[4 * u + 1] = a.y; v[4 * u + 2] = a.z; v[4 * u + 3] = a.w;
    }
    uint4 b0, b1;
    b0.x = pack_bf2(v[0], v[1]);  b0.y = pack_bf2(v[2], v[3]);
    b0.z = pack_bf2(v[4], v[5]);  b0.w = pack_bf2(v[6], v[7]);
    b1.x = pack_bf2(v[8], v[9]);  b1.y = pack_bf2(v[10], v[11]);
    b1.z = pack_bf2(v[12], v[13]); b1.w = pack_bf2(v[14], v[15]);
    uint4* ob = (uint4*)(Xb + (size_t)row * 4096);
    ob[t * 2] = b0;
    ob[t * 2 + 1] = b1;
    uint4 w8;
    w8.x = pack_fp8x4(v[0] * FP8_SCALE, v[1] * FP8_SCALE, v[2] * FP8_SCALE, v[3] * FP8_SCALE);
    w8.y = pack_fp8x4(v[4] * FP8_SCALE, v[5] * FP8_SCALE, v[6] * FP8_SCALE, v[7] * FP8_SCALE);
    w8.z = pack_fp8x4(v[8] * FP8_SCALE, v[9] * FP8_SCALE, v[10] * FP8_SCALE, v[11] * FP8_SCALE);
    w8.w = pack_fp8x4(v[12] * FP8_SCALE, v[13] * FP8_SCALE, v[14] * FP8_SCALE, v[15] * FP8_SCALE);
    int tb = (t & ~7) | ((t & 7) ^ (row & 7));
    ((uint4*)(Xf8 + (size_t)row * 4096))[tb] = w8;
}

// V transpose (sums split-K fp32 partials, kappa-permuted cols). 512 blocks: 32 x 16.
__global__ __launch_bounds__(256) void vtr_k(const float* __restrict__ Vpart,
                                             u16* __restrict__ Vt) {
    __shared__ u16 t[64][65];
    int bx = blockIdx.x;
    int s0 = (bx & 31) * 64, c0 = (bx >> 5) * 64;
    int x = threadIdx.x & 63, y4 = threadIdx.x >> 6;
    const float* Vp0 = Vpart;
    const float* Vp1 = Vpart + (size_t)2048 * 1024;
    for (int i = 0; i < 16; i++) {
        int r = y4 * 16 + i;
        size_t idx = (size_t)(s0 + r) * 1024 + c0 + x;
        t[r][x] = f2bf(Vp0[idx] + Vp1[idx]);
    }
    __syncthreads();
    for (int i = 0; i < 16; i++) {
        int r = y4 * 16 + i;
        int xk = 4 * (x & 15) + (x >> 4);  // kappa permutation within 64-key tile
        Vt[(size_t)(c0 + r) * 2048 + s0 + xk] = t[x][r];
    }
}

// ---------------- merged QKV GEMM: R2 structure + depth-2 counted-vmcnt pipeline ----------------
// 256 threads, 4 waves (2M x 2N, wave tile 64x64), 128x128 tiles, LDS 2 x 32KB dbuf (64 KB
// dynamic -> 2 blocks/CU). 8 async_copy16/thread/tile -> steady vmcnt(8), peel 8 -> 0.
// blocks x<40: Q,K via MX-fp8 (BK=128B, 32 tiles) + fused RoPE epilogue.
// blocks x in [40,56): V via bf16 (BK=64, 2-way split-K, 32 tiles), fp32 partials.

#define QKV_BAR() asm volatile("s_barrier" ::: "memory")

#define QK_STAGE(bufi, kt) do {                                                   \
    u8* la_ = S8 + (bufi) * 32768 + w * 4096;                                     \
    u8* lb_ = la_ + 16384;                                                        \
    const int k0_ = (kt) * 128;                                                   \
    _Pragma("unroll")                                                             \
    for (int t_ = 0; t_ < 4; t_++)                                                \
        async_copy16(AgQ + (size_t)t_ * 8 * 4096 + k0_, la_ + t_ * 1024);         \
    _Pragma("unroll")                                                             \
    for (int t_ = 0; t_ < 4; t_++)                                                \
        async_copy16(BgQ + (size_t)t_ * 8 * 4096 + k0_, lb_ + t_ * 1024);         \
} while (0)

#define QK_COMPUTE(bufi) do {                                                     \
    const u8* la_ = S8 + (bufi) * 32768;                                          \
    const u8* lb_ = la_ + 16384;                                                  \
    union { i32x8 v8; i32x4 v4[2]; } u_;                                          \
    i32x8 bfv[4], af0, af1;                                                       \
    _Pragma("unroll")                                                             \
    for (int j_ = 0; j_ < 4; j_++) {                                              \
        const int r_ = (wn + j_ * 16 + l16) * 128;                                \
        u_.v4[0] = *(const i32x4*)&lb_[r_ + s0b];                                 \
        u_.v4[1] = *(const i32x4*)&lb_[r_ + s1b];                                 \
        bfv[j_] = u_.v8;                                                          \
    }                                                                             \
    { const int r_ = (wm + l16) * 128;                                            \
      u_.v4[0] = *(const i32x4*)&la_[r_ + s0b];                                   \
      u_.v4[1] = *(const i32x4*)&la_[r_ + s1b]; af0 = u_.v8; }                    \
    { const int r_ = (wm + 16 + l16) * 128;                                       \
      u_.v4[0] = *(const i32x4*)&la_[r_ + s0b];                                   \
      u_.v4[1] = *(const i32x4*)&la_[r_ + s1b]; af1 = u_.v8; }                    \
    asm volatile("s_waitcnt lgkmcnt(0)" ::: "memory");                            \
    __builtin_amdgcn_sched_barrier(0);                                            \
    __builtin_amdgcn_s_setprio(1);                                                \
    _Pragma("unroll")                                                             \
    for (int j_ = 0; j_ < 4; j_++) {                                              \
        acc[0][j_] = __builtin_amdgcn_mfma_scale_f32_16x16x128_f8f6f4(af0, bfv[j_], acc[0][j_], 0, 0, 0, 0x7F7F7F7F, 0, 0x7F7F7F7F); \
        acc[1][j_] = __builtin_amdgcn_mfma_scale_f32_16x16x128_f8f6f4(af1, bfv[j_], acc[1][j_], 0, 0, 0, 0x7F7F7F7F, 0, 0x7F7F7F7F); \
    }                                                                             \
    __builtin_amdgcn_s_setprio(0);                                                \
    { const int r_ = (wm + 32 + l16) * 128;                                       \
      u_.v4[0] = *(const i32x4*)&la_[r_ + s0b];                                   \
      u_.v4[1] = *(const i32x4*)&la_[r_ + s1b]; af0 = u_.v8; }                    \
    { const int r_ = (wm + 48 + l16) * 128;                                       \
      u_.v4[0] = *(const i32x4*)&la_[r_ + s0b];                                   \
      u_.v4[1] = *(const i32x4*)&la_[r_ + s1b]; af1 = u_.v8; }                    \
    asm volatile("s_waitcnt lgkmcnt(0)" ::: "memory");                            \
    __builtin_amdgcn_sched_barrier(0);                                            \
    __builtin_amdgcn_s_setprio(1);                                                \
    _Pragma("unroll")                                                             \
    for (int j_ = 0; j_ < 4; j_++) {                                              \
        acc[2][j_] = __builtin_amdgcn_mfma_scale_f32_16x16x128_f8f6f4(af0, bfv[j_], acc[2][j_], 0, 0, 0, 0x7F7F7F7F, 0, 0x7F7F7F7F); \
        acc[3][j_] = __builtin_amdgcn_mfma_scale_f32_16x16x128_f8f6f4(af1, bfv[j_], acc[3][j_], 0, 0, 0, 0x7F7F7F7F, 0, 0x7F7F7F7F); \
    }                                                                             \
    __builtin_amdgcn_s_setprio(0);                                                \
} while (0)

#define V_STAGE(bufi, kt) do {                                                    \
    u16* a0_ = (u16*)(S8 + (bufi) * 32768);                                       \
    u16* a1_ = a0_ + 4096;                                                        \
    u16* b0_ = a0_ + 8192;                                                        \
    u16* b1_ = a0_ + 12288;                                                       \
    const int k0_ = (kt) * 64;                                                    \
    async_copy16(AgV + k0_,                          a0_ + w * 512);              \
    async_copy16(AgV + (size_t)64 * 4096 + k0_,      a0_ + (w + 4) * 512);        \
    async_copy16(AgV + k0_ + 32,                     a1_ + w * 512);              \
    async_copy16(AgV + (size_t)64 * 4096 + k0_ + 32, a1_ + (w + 4) * 512);        \
    async_copy16(BgV + k0_,                          b0_ + w * 512);              \
    async_copy16(BgV + (size_t)64 * 4096 + k0_,      b0_ + (w + 4) * 512);        \
    async_copy16(BgV + k0_ + 32,                     b1_ + w * 512);              \
    async_copy16(BgV + (size_t)64 * 4096 + k0_ + 32, b1_ + (w + 4) * 512);        \
} while (0)

#define V_COMPUTE(bufi) do {                                                      \
    const u16* base_ = (const u16*)(S8 + (bufi) * 32768);                         \
    _Pragma("unroll")                                                             \
    for (int kk_ = 0; kk_ < 2; kk_++) {                                           \
        const u16* la_ = base_ + kk_ * 4096;                                      \
        const u16* lb_ = base_ + 8192 + kk_ * 4096;                               \
        bf16x8 af[4], bfv[4];                                                     \
        _Pragma("unroll")                                                         \
        for (int i_ = 0; i_ < 4; i_++)                                            \
            af[i_] = *(const bf16x8*)&la_[(wm + i_ * 16 + l16) * 32 + quad * 8];  \
        _Pragma("unroll")                                                         \
        for (int j_ = 0; j_ < 4; j_++)                                            \
            bfv[j_] = *(const bf16x8*)&lb_[(wn + j_ * 16 + l16) * 32 + quad * 8]; \
        asm volatile("s_waitcnt lgkmcnt(0)" ::: "memory");                        \
        __builtin_amdgcn_sched_barrier(0);                                        \
        __builtin_amdgcn_s_setprio(1);                                            \
        _Pragma("unroll")                                                         \
        for (int i_ = 0; i_ < 4; i_++)                                            \
            _Pragma("unroll")                                                     \
            for (int j_ = 0; j_ < 4; j_++)                                        \
                acc[i_][j_] = __builtin_amdgcn_mfma_f32_16x16x32_bf16(af[i_], bfv[j_], acc[i_][j_], 0, 0, 0); \
        __builtin_amdgcn_s_setprio(0);                                            \
    }                                                                             \
} while (0)

__global__ __launch_bounds__(256, 2) void gemm_qkv_k(const u8* __restrict__ Xf8,
                                                     const u16* __restrict__ Xb,
                                                     const u8* __restrict__ Wqk,
                                                     const u16* __restrict__ Wv,
                                                     u16* __restrict__ QKV,
                                                     float* __restrict__ Vpart,
                                                     const float* __restrict__ cosv,
                                                     const float* __restrict__ sinv) {
    extern __shared__ u8 S8[];                 // 2 * 32768 = 64 KB
    const int tid = threadIdx.x;
    const int w = tid >> 6, lane = tid & 63;
    const int quad = lane >> 4, l16 = lane & 15;
    const int bm0 = blockIdx.y * 128;
    const int wm = (w >> 1) * 64, wn = (w & 1) * 64;
    const int swz = l16 & 7;                   // fragment row & 7
    const int s0b = ((quad * 2) ^ swz) * 16;   // fp8 16B-slot byte offsets
    const int s1b = ((quad * 2 + 1) ^ swz) * 16;

    if (blockIdx.x < 40) {
        // ---------------- Q,K MX-fp8 path ----------------
        const int bn0 = blockIdx.x * 128;
        const u8* AgQ = Xf8 + (size_t)(bm0 + w * 32 + (lane >> 3)) * 4096 + (lane & 7) * 16;
        const u8* BgQ = Wqk + (size_t)(bn0 + w * 32 + (lane >> 3)) * 4096 + (lane & 7) * 16;
        f32x4 acc[4][4] = {};

        QK_STAGE(0, 0);
        QK_STAGE(1, 1);
        asm volatile("s_waitcnt vmcnt(8)" ::: "memory");   // tile 0 landed
        QKV_BAR();
        int cur = 0;
        for (int t = 0; t < 30; ++t) {
            QK_COMPUTE(cur);
            QKV_BAR();                                     // everyone done reading buf[cur]
            QK_STAGE(cur, t + 2);
            asm volatile("s_waitcnt vmcnt(8)" ::: "memory");  // tile t+1 landed
            QKV_BAR();
            cur ^= 1;
        }
        QK_COMPUTE(0);                                     // tile 30
        asm volatile("s_waitcnt vmcnt(0)" ::: "memory");   // tile 31 landed
        QKV_BAR();
        QK_COMPUTE(1);                                     // tile 31

        // fused RoPE epilogue: with the P column permutation, lane's cols hold
        //   j even -> head-dim d1, j odd -> head-dim d1+64 (same lane, same rows).
        const float qsc = (bn0 < 4096) ? 0.08838834764831845f : 1.0f;  // 1/sqrt(128) for Q
        const int hb = (wn ? 32 : 0) + l16;
#pragma unroll
        for (int i = 0; i < 4; i++) {
            const int row = bm0 + wm + i * 16 + quad * 4;
#pragma unroll
            for (int jp = 0; jp < 2; jp++) {       // pair groups (j=0,1) and (j=2,3)
                const int d1 = hb + jp * 16;
                const int ce = bn0 + wn + jp * 32 + l16;
#pragma unroll
                for (int r = 0; r < 4; r++) {
                    const int s = row + r;
                    const float c  = cosv[s * 128 + d1];
                    const float sn = sinv[s * 128 + d1];
                    const float x1 = acc[i][jp * 2][r]     * FP8_UNSCALE;
                    const float x2 = acc[i][jp * 2 + 1][r] * FP8_UNSCALE;
                    QKV[(size_t)s * 6144 + ce]      = f2bf((x1 * c - x2 * sn) * qsc);
                    QKV[(size_t)s * 6144 + ce + 16] = f2bf((x2 * c + x1 * sn) * qsc);
                }
            }
        }
    } else {
        // ---------------- V bf16 path (2-way split-K) ----------------
        const int vx = blockIdx.x - 40;        // 16 slots: 8 n-tiles x 2 k-slices
        const int bn0 = (vx & 7) * 128;
        const int kslice = vx >> 3;
        const int kb = kslice * 2048;
        const int r0 = w * 16 + (lane >> 2);
        const int c0 = (lane & 3) * 8;
        const u16* AgV = Xb + (size_t)(bm0 + r0) * 4096 + kb + c0;
        const u16* BgV = Wv + (size_t)(bn0 + r0) * 4096 + kb + c0;
        f32x4 acc[4][4] = {};

        V_STAGE(0, 0);
        V_STAGE(1, 1);
        asm volatile("s_waitcnt vmcnt(8)" ::: "memory");
        QKV_BAR();
        int cur = 0;
        for (int t = 0; t < 30; ++t) {
            V_COMPUTE(cur);
            QKV_BAR();
            V_STAGE(cur, t + 2);
            asm volatile("s_waitcnt vmcnt(8)" ::: "memory");
            QKV_BAR();
            cur ^= 1;
        }
        V_COMPUTE(0);                                      // tile 30
        asm volatile("s_waitcnt vmcnt(0)" ::: "memory");   // tile 31 landed
        QKV_BAR();
        V_COMPUTE(1);                                      // tile 31

        float* Vp = Vpart + (size_t)kslice * 2048 * 1024;
#pragma unroll
        for (int i = 0; i < 4; i++) {
            const int row = bm0 + wm + i * 16 + quad * 4;
#pragma unroll
            for (int j = 0; j < 4; j++) {
                const int col = bn0 + wn + j * 16 + l16;
#pragma unroll
                for (int r = 0; r < 4; r++)
                    Vp[(size_t)(row + r) * 1024 + col] = acc[i][j][r];
            }
        }
    }
}

// ---------------- O-projection GEMM: single-pass K=4096, depth-3 counted-vmcnt pipeline --------
// BM=256, BN=128, BK=64. 512 thr (8 waves, 4Mx2N, 64x64/wave). LDS: 3 x 48KB buffers (dynamic).
// Stage uses inverse-swizzled global source (linear LDS dest); ds_read applies slot^=(row&7)
// -> conflict-free b128 batches. vmcnt(12) steady state (2 tiles in flight), peel 12->6->0.
// Direct fp32 store to d_out: no split-K, no atomics, no memset, no reduce.

#define GO_STAGE(bufi, kt) do {                                                   \
    u16* la_ = S + (bufi) * 24576;                                                \
    u16* lb_ = la_ + 16384;                                                       \
    const int k0_ = (kt) * 64;                                                    \
    _Pragma("unroll")                                                             \
    for (int u = 0; u < 4; u++)                                                   \
        async_copy16(Asrc + (size_t)u * 64 * 4096 + k0_, la_ + u * 4096 + sdst);  \
    _Pragma("unroll")                                                             \
    for (int u = 0; u < 2; u++)                                                   \
        async_copy16(Bsrc + (size_t)u * 64 * 4096 + k0_, lb_ + u * 4096 + sdst);  \
} while (0)

#define GO_COMPUTE(bufi) do {                                                     \
    const u16* la_ = S + (bufi) * 24576;                                          \
    const u16* lb_ = la_ + 16384;                                                 \
    bf16x8 bfr[4][2], afr[2][2];                                                  \
    _Pragma("unroll")                                                             \
    for (int j = 0; j < 4; j++) {                                                 \
        const int rb_ = (wn + j * 16 + l16) * 64;                                 \
        bfr[j][0] = *(const bf16x8*)&lb_[rb_ + o0];                               \
        bfr[j][1] = *(const bf16x8*)&lb_[rb_ + o1];                               \
    }                                                                             \
    _Pragma("unroll")                                                             \
    for (int i = 0; i < 2; i++) {                                                 \
        const int ra_ = (wm + i * 16 + l16) * 64;                                 \
        afr[i][0] = *(const bf16x8*)&la_[ra_ + o0];                               \
        afr[i][1] = *(const bf16x8*)&la_[ra_ + o1];                               \
    }                                                                             \
    asm volatile("s_waitcnt lgkmcnt(0)" ::: "memory");                            \
    __builtin_amdgcn_sched_barrier(0);                                            \
    __builtin_amdgcn_s_setprio(1);                                                \
    _Pragma("unroll")                                                             \
    for (int i = 0; i < 2; i++)                                                   \
        _Pragma("unroll")                                                         \
        for (int j = 0; j < 4; j++) {                                             \
            acc[i][j] = __builtin_amdgcn_mfma_f32_16x16x32_bf16(afr[i][0], bfr[j][0], acc[i][j], 0, 0, 0); \
            acc[i][j] = __builtin_amdgcn_mfma_f32_16x16x32_bf16(afr[i][1], bfr[j][1], acc[i][j], 0, 0, 0); \
        }                                                                         \
    __builtin_amdgcn_s_setprio(0);                                                \
    _Pragma("unroll")                                                             \
    for (int i = 0; i < 2; i++) {                                                 \
        const int ra_ = (wm + (i + 2) * 16 + l16) * 64;                           \
        afr[i][0] = *(const bf16x8*)&la_[ra_ + o0];                               \
        afr[i][1] = *(const bf16x8*)&la_[ra_ + o1];                               \
    }                                                                             \
    asm volatile("s_waitcnt lgkmcnt(0)" ::: "memory");                            \
    __builtin_amdgcn_sched_barrier(0);                                            \
    __builtin_amdgcn_s_setprio(1);                                                \
    _Pragma("unroll")                                                             \
    for (int i = 0; i < 2; i++)                                                   \
        _Pragma("unroll")                                                         \
        for (int j = 0; j < 4; j++) {                                             \
            acc[i + 2][j] = __builtin_amdgcn_mfma_f32_16x16x32_bf16(afr[i][0], bfr[j][0], acc[i + 2][j], 0, 0, 0); \
            acc[i + 2][j] = __builtin_amdgcn_mfma_f32_16x16x32_bf16(afr[i][1], bfr[j][1], acc[i + 2][j], 0, 0, 0); \
        }                                                                         \
    __builtin_amdgcn_s_setprio(0);                                                \
} while (0)

#define GO_BAR() asm volatile("s_barrier" ::: "memory")

__global__ __launch_bounds__(512, 2) void gemm_o_k(const u16* __restrict__ A,
                                                   const u16* __restrict__ B,
                                                   float* __restrict__ Out) {
    extern __shared__ u16 S[];                 // 3 * 49152 B = 144 KB
    const int tid = threadIdx.x;
    const int w = tid >> 6, lane = tid & 63;
    const int quad = lane >> 4, l16 = lane & 15;
    // XCD-bijective swizzle over 256 blocks: each XCD gets one contiguous m-row (A-panel L2-resident)
    const int linear = blockIdx.y * 32 + blockIdx.x;
    const int wgid = (linear & 7) * 32 + (linear >> 3);
    const int bm0 = (wgid >> 5) * 256;
    const int bn0 = (wgid & 31) * 128;
    const int wm = (w >> 1) * 64;              // 4 waves along M
    const int wn = (w & 1) * 64;               // 2 waves along N
    // staging: thread -> (row = u*64 + tid>>3, col16B = (tid&7) ^ (row&7))  [inverse swizzle]
    const int sr = tid >> 3;
    const int scg = ((tid & 7) ^ (sr & 7)) * 8;
    const int sdst = tid * 8;                  // u16 units (16B/thread)
    const u16* Asrc = A + (size_t)(bm0 + sr) * 4096 + scg;
    const u16* Bsrc = B + (size_t)(bn0 + sr) * 4096 + scg;
    // fragment read swizzle: slot = ((kk<<2)|quad) ^ (row&7); row&7 == l16&7 here
    const int swz = l16 & 7;
    const int o0 = (quad ^ swz) * 8;           // u16 offset for kk=0
    const int o1 = ((4 | quad) ^ swz) * 8;     // u16 offset for kk=1

    f32x4 acc[4][4] = {};

    GO_STAGE(0, 0);
    GO_STAGE(1, 1);
    GO_STAGE(2, 2);
    asm volatile("s_waitcnt vmcnt(12)" ::: "memory");   // tile 0 landed
    GO_BAR();

    int cur = 0;
    for (int t = 0; t < 61; ++t) {
        GO_COMPUTE(cur);
        GO_BAR();                                        // all waves done reading buf[cur]
        GO_STAGE(cur, t + 3);
        asm volatile("s_waitcnt vmcnt(12)" ::: "memory"); // tile t+1 landed (t+2,t+3 in flight)
        GO_BAR();
        cur = (cur == 2) ? 0 : cur + 1;
    }
    // t = 61 (buf 1): tile 63's 6 loads may still be in flight
    GO_COMPUTE(1);
    asm volatile("s_waitcnt vmcnt(6)" ::: "memory");      // tile 62 landed
    GO_BAR();
    // t = 62 (buf 2)
    GO_COMPUTE(2);
    asm volatile("s_waitcnt vmcnt(0)" ::: "memory");      // tile 63 landed
    GO_BAR();
    // t = 63 (buf 0)
    GO_COMPUTE(0);

#pragma unroll
    for (int i = 0; i < 4; i++) {
        const int row = bm0 + wm + i * 16 + quad * 4;
#pragma unroll
        for (int j = 0; j < 4; j++) {
            const int col = bn0 + wn + j * 16 + l16;
#pragma unroll
            for (int r = 0; r < 4; r++)
                Out[(size_t)(row + r) * 4096 + col] = acc[i][j][r];
        }
    }
}

// ---------------- fused flash attention (GQA, causal, no-max softmax) ----------------

__global__ __launch_bounds__(256) void attn_k(const u16* __restrict__ Qb,
                                              const u16* __restrict__ Kb,
                                              const u16* __restrict__ Vt,
                                              u16* __restrict__ Ob,
                                              int qstride, int kstride) {
    __shared__ u16 ldsK[4 * 64 * 32];   // [kk][key][hd32]
    __shared__ u16 ldsV[2 * 128 * 32];  // [ks][d][kappa32]
    __shared__ u16 ldsP[4][32 * 72];    // per-wave [m 32][kappa 64 + pad 8]
    const int h = blockIdx.x;
    const int qt = (int)gridDim.y - 1 - (int)blockIdx.y;  // heavy tiles first
    const int kvh = h >> 2;
    const int tid = threadIdx.x;
    const int w = tid >> 6, lane = tid & 63;
    const int quad = lane >> 4, l16 = lane & 15;
    const int q0 = qt * 128;
    const int wrow = q0 + w * 32;

    bf16x8 qf[2][4];
#pragma unroll
    for (int mi = 0; mi < 2; mi++)
#pragma unroll
        for (int kk = 0; kk < 4; kk++)
            qf[mi][kk] = *(const bf16x8*)&Qb[(size_t)(wrow + mi * 16 + l16) * qstride +
                                             h * 128 + kk * 32 + quad * 8];

    const u16* kp[4]; const u16* vp[4];
    u16* ldk[4]; u16* ldv[4];
#pragma unroll
    for (int t = 0; t < 4; t++) {
        int wl = w + t * 4;
        int kk = wl >> 2, part = wl & 3;
        kp[t] = Kb + (size_t)(part * 16 + (lane >> 2)) * kstride + kvh * 128 + kk * 32 + (lane & 3) * 8;
        int ks2 = wl >> 3, p2 = wl & 7;
        vp[t] = Vt + (size_t)(kvh * 128 + p2 * 16 + (lane >> 2)) * 2048 + ks2 * 32 + (lane & 3) * 8;
        ldk[t] = ldsK + wl * 512;
        ldv[t] = ldsV + wl * 512;
    }

    f32x4 acc_o[2][8] = {};
    float lrow[2][4] = {};

    const int nk = 2 * (qt + 1);
    for (int kn = 0; kn < nk; kn++) {
        const int g0 = kn * 64;
#pragma unroll
        for (int t = 0; t < 4; t++) async_copy16(kp[t], ldk[t]);
#pragma unroll
        for (int t = 0; t < 4; t++) async_copy16(vp[t], ldv[t]);
#pragma unroll
        for (int t = 0; t < 4; t++) { kp[t] += (size_t)64 * kstride; vp[t] += 64; }
        __syncthreads();

        if (g0 <= wrow + 31) {
            f32x4 accs[2][4] = {};
#pragma unroll
            for (int kk = 0; kk < 4; kk++) {
                bf16x8 bfrag[4];
#pragma unroll
                for (int ni = 0; ni < 4; ni++)
                    bfrag[ni] = *(const bf16x8*)&ldsK[kk * 2048 + (ni * 16 + l16) * 32 + quad * 8];
                __builtin_amdgcn_s_setprio(1);
#pragma unroll
                for (int mi = 0; mi < 2; mi++)
#pragma unroll
                    for (int ni = 0; ni < 4; ni++)
                        accs[mi][ni] = __builtin_amdgcn_mfma_f32_16x16x32_bf16(
                            qf[mi][kk], bfrag[ni], accs[mi][ni], 0, 0, 0);
                __builtin_amdgcn_s_setprio(0);
            }
            const bool diag = (g0 + 63 > wrow);
            int kidx[4];
#pragma unroll
            for (int ni = 0; ni < 4; ni++) kidx[ni] = g0 + ni * 16 + l16;
#pragma unroll
            for (int mi = 0; mi < 2; mi++) {
#pragma unroll
                for (int r = 0; r < 4; r++) {
                    const int qrow = wrow + mi * 16 + quad * 4 + r;
                    float p[4];
#pragma unroll
                    for (int ni = 0; ni < 4; ni++) {
                        float s = accs[mi][ni][r];
                        if (diag && (kidx[ni] > qrow)) s = -1e30f;
                        p[ni] = __expf(s);
                    }
                    lrow[mi][r] += (p[0] + p[1]) + (p[2] + p[3]);
                    uint2 pk;
                    pk.x = pack_bf2(p[0], p[1]);
                    pk.y = pack_bf2(p[2], p[3]);
                    *(uint2*)&ldsP[w][(mi * 16 + quad * 4 + r) * 72 + l16 * 4] = pk;
                }
            }
#pragma unroll
            for (int ks = 0; ks < 2; ks++) {
                bf16x8 pa[2];
#pragma unroll
                for (int mi = 0; mi < 2; mi++)
                    pa[mi] = *(const bf16x8*)&ldsP[w][(mi * 16 + l16) * 72 + ks * 32 + quad * 8];
                __builtin_amdgcn_s_setprio(1);
#pragma unroll
                for (int oj = 0; oj < 8; oj++) {
                    bf16x8 vb = *(const bf16x8*)&ldsV[ks * 4096 + (oj * 16 + l16) * 32 + quad * 8];
#pragma unroll
                    for (int mi = 0; mi < 2; mi++)
                        acc_o[mi][oj] = __builtin_amdgcn_mfma_f32_16x16x32_bf16(
                            pa[mi], vb, acc_o[mi][oj], 0, 0, 0);
                }
                __builtin_amdgcn_s_setprio(0);
            }
        }
        __syncthreads();
    }
#pragma unroll
    for (int mi = 0; mi < 2; mi++)
#pragma unroll
        for (int r = 0; r < 4; r++) {
            float l = lrow[mi][r];
            l += __shfl_xor(l, 1);
            l += __shfl_xor(l, 2);
            l += __shfl_xor(l, 4);
            l += __shfl_xor(l, 8);
            const float inv = 1.0f / l;
            const int qrow = wrow + mi * 16 + quad * 4 + r;
#pragma unroll
            for (int oj = 0; oj < 8; oj++)
                Ob[(size_t)qrow * 4096 + h * 128 + oj * 16 + l16] =
                    f2bf(acc_o[mi][oj][r] * inv);
        }
}

// ---------------- launch ----------------

extern "C" void kernel_launch(void* const* d_in, const int* in_sizes, int n_in,
                              void* d_out, int out_size, void* d_ws, size_t ws_size,
                              hipStream_t stream) {
    (void)in_sizes; (void)n_in; (void)out_size; (void)ws_size;
    const float* hidden = (const float*)d_in[0];
    const float* Wq = (const float*)d_in[1];
    const float* Wk = (const float*)d_in[2];
    const float* Wv = (const float*)d_in[3];
    const float* Wo = (const float*)d_in[4];
    const float* cosv = (const float*)d_in[5];
    const float* sinv = (const float*)d_in[6];
    const int* qoc = (const int*)d_in[8];
    const int* qor = (const int*)d_in[9];
    const int* koc = (const int*)d_in[10];
    const int* kor = (const int*)d_in[11];
    const int* voc = (const int*)d_in[12];
    const int* vor = (const int*)d_in[13];
    const int* ooc = (const int*)d_in[14];
    const int* oor = (const int*)d_in[15];

    char* ws = (char*)d_ws;
    size_t off = 0;
    // persistent across the whole pipeline:
    int* invq = (int*)(ws + off); off += 16384;
    int* invk = (int*)(ws + off); off += 16384;
    int* invv = (int*)(ws + off); off += 16384;
    int* invo = (int*)(ws + off); off += 16384;
    u16* Wop   = (u16*)(ws + off); off += (size_t)4096 * 4096 * 2;   // 33.5 MB (live at O-proj)
    u16* Xb    = (u16*)(ws + off); off += (size_t)2048 * 4096 * 2;   // 16.8 MB (live as Attb)
    u8*  Wqkf8 = (u8*)(ws + off);  off += (size_t)5120 * 4096;       // 21.0 MB
    u16* Wvp   = (u16*)(ws + off); off += (size_t)1024 * 4096 * 2;   //  8.4 MB
    u8*  Xf8   = (u8*)(ws + off);  off += (size_t)2048 * 4096;       //  8.4 MB
    u16* QKVb  = (u16*)(ws + off); off += (size_t)2048 * 6144 * 2;   // 25.2 MB
    u16* Vtb   = (u16*)(ws + off); off += (size_t)1024 * 2048 * 2;   //  4.2 MB
    float* Vpart = (float*)(ws + off); off += (size_t)2 * 2048 * 1024 * 4;  // 16.8 MB
    u16* Attb  = Xb;   // Xb dead after gemm_qkv_k; reuse for attention output

    inv4_k<<<64, 256, 0, stream>>>(qoc, koc, voc, ooc, invq, invk, invv, invo);
    permw4_k<<<10240, 256, 0, stream>>>(Wq, Wk, Wv, Wo, qor, kor, vor, oor,
                                        invq, invk, invv, invo, Wqkf8, Wvp, Wop);
    cvt_k<<<2048, 256, 0, stream>>>(hidden, Xb, Xf8);

    // QKV: Q,K via MX-fp8 (+fused RoPE/scale) + V via bf16 split-K2 -> QKVb + Vpart
    gemm_qkv_k<<<dim3(56, 16), 256, 65536, stream>>>(Xf8, Xb, Wqkf8, Wvp, QKVb, Vpart,
                                                     cosv, sinv);

    // Vt build (sums split-K partials, kappa permutation)
    vtr_k<<<512, 256, 0, stream>>>(Vpart, Vtb);

    // attention -> Attb [2048][4096]  (reuses Xb storage)
    attn_k<<<dim3(32, 16), 256, 0, stream>>>(QKVb, QKVb + 4096, Vtb, Attb, 6144, 6144);

    // O-projection: single-pass pipelined bf16 GEMM, direct fp32 store
    gemm_o_k<<<dim3(32, 8), 512, 147456, stream>>>(Attb, Wop, (float*)d_out);
}

// Round 5
// 467.994 us; speedup vs baseline: 1.0641x; 1.0079x over previous
//
#include <hip/hip_runtime.h>

typedef unsigned short u16;
typedef unsigned char u8;
typedef __bf16 bf16x8 __attribute__((ext_vector_type(8)));
typedef float f32x4 __attribute__((ext_vector_type(4)));
typedef int i32x4 __attribute__((ext_vector_type(4)));
typedef int i32x8 __attribute__((ext_vector_type(8)));

__device__ __forceinline__ u16 f2bf(float f) {
    unsigned u = __float_as_uint(f);
    unsigned r = (u + 0x7fffu + ((u >> 16) & 1u)) >> 16;
    return (u16)r;
}
__device__ __forceinline__ float bf2f(u16 h) {
    return __uint_as_float(((unsigned)h) << 16);
}
// pack two floats to bf16x2 (lo in low half), round-half-up, single v_perm
__device__ __forceinline__ unsigned pack_bf2(float lo, float hi) {
    unsigned a = __float_as_uint(hi) + 0x8000u;
    unsigned b = __float_as_uint(lo) + 0x8000u;
    return __builtin_amdgcn_perm(a, b, 0x07060302u);
}
// pack 4 floats to 4 fp8 e4m3 bytes
__device__ __forceinline__ unsigned pack_fp8x4(float a, float b, float c, float d) {
    unsigned w = __builtin_amdgcn_cvt_pk_fp8_f32(a, b, 0, false);
    w = __builtin_amdgcn_cvt_pk_fp8_f32(c, d, w, true);
    return w;
}
__device__ __forceinline__ void async_copy16(const void* g, void* l) {
    __builtin_amdgcn_global_load_lds((__attribute__((address_space(1))) void*)(void*)g,
                                     (__attribute__((address_space(3))) void*)l, 16, 0, 0);
}

#define FP8_SCALE 64.0f          // pre-scale before e4m3 quant (avoids subnormals)
#define FP8_UNSCALE (1.0f / 4096.0f)  // (1/64)^2 applied at GEMM epilogue

// ---------------- prep kernels ----------------

__global__ void inv4_k(const int* __restrict__ q, const int* __restrict__ k,
                       const int* __restrict__ v, const int* __restrict__ o,
                       int* __restrict__ invq, int* __restrict__ invk,
                       int* __restrict__ invv, int* __restrict__ invo) {
    int i = blockIdx.x * 256 + threadIdx.x;   // grid 64 -> 16384 = 4*4096
    int a = i >> 12, j = i & 4095;
    const int* p = a == 0 ? q : a == 1 ? k : a == 2 ? v : o;
    int* inv = a == 0 ? invq : a == 1 ? invk : a == 2 ? invv : invo;
    inv[p[j]] = j;
}

// Weight permutations. Q,K rows -> fp8 (x64, XOR-swizzled 16B blocks); V,O rows -> bf16.
// Q,K additionally get a head-dim COLUMN permutation P (applied by selecting permuted
// weight rows) so RoPE pairs (d, d+64) land in adjacent j-fragments of one lane in the
// MFMA C-layout.  QK^T is invariant: Q and K share the same P.
//   P[hd] = (hd&15) | ((b&1)<<6) | ((b&2)<<3) | ((hd&64)>>1),  b = hd>>4
__global__ __launch_bounds__(256) void permw4_k(
    const float* __restrict__ Wq, const float* __restrict__ Wk,
    const float* __restrict__ Wv, const float* __restrict__ Wo,
    const int* __restrict__ qor, const int* __restrict__ kor,
    const int* __restrict__ vor, const int* __restrict__ oor,
    const int* __restrict__ invq, const int* __restrict__ invk,
    const int* __restrict__ invv, const int* __restrict__ invo,
    u8* __restrict__ Wqkf8, u16* __restrict__ Wvp, u16* __restrict__ Wop) {
    __shared__ float rowbuf[4096];
    int j = blockIdx.x;
    const float* W; const int* rp; const int* inv; int row; int f8;
    u8* out8 = nullptr; u16* out16 = nullptr;
    if (j < 4096)      { W = Wq; rp = qor; inv = invq; row = j;        out8 = Wqkf8 + (size_t)j * 4096; f8 = 1; }
    else if (j < 5120) { W = Wk; rp = kor; inv = invk; row = j - 4096; out8 = Wqkf8 + (size_t)j * 4096; f8 = 1; }
    else if (j < 6144) { W = Wv; rp = vor; inv = invv; row = j - 5120; out16 = Wvp + (size_t)(j - 5120) * 4096; f8 = 0; }
    else               { W = Wo; rp = oor; inv = invo; row = j - 6144; out16 = Wop + (size_t)(j - 6144) * 4096; f8 = 0; }
    if (f8) {   // head-dim column permutation for Q,K (RoPE pairing)
        int hd = row & 127, b = hd >> 4;
        row = (row & ~127) | ((hd & 15) | ((b & 1) << 6) | ((b & 2) << 3) | ((hd & 64) >> 1));
    }
    const float4* wr4 = (const float4*)(W + (size_t)rp[row] * 4096);
#pragma unroll
    for (int t = 0; t < 4; t++)
        ((float4*)rowbuf)[threadIdx.x + t * 256] = wr4[threadIdx.x + t * 256];
    __syncthreads();
    if (f8) {
        int t = threadIdx.x;                       // one 16B block per thread
        const int4* inv4p = (const int4*)inv;
        float v[16];
#pragma unroll
        for (int u = 0; u < 4; u++) {
            int4 ix = inv4p[t * 4 + u];
            v[4 * u + 0] = rowbuf[ix.x] * FP8_SCALE;
            v[4 * u + 1] = rowbuf[ix.y] * FP8_SCALE;
            v[4 * u + 2] = rowbuf[ix.z] * FP8_SCALE;
            v[4 * u + 3] = rowbuf[ix.w] * FP8_SCALE;
        }
        uint4 wv;
        wv.x = pack_fp8x4(v[0], v[1], v[2], v[3]);
        wv.y = pack_fp8x4(v[4], v[5], v[6], v[7]);
        wv.z = pack_fp8x4(v[8], v[9], v[10], v[11]);
        wv.w = pack_fp8x4(v[12], v[13], v[14], v[15]);
        int tb = (t & ~7) | ((t & 7) ^ (j & 7));   // XOR swizzle within 128B segment
        ((uint4*)out8)[tb] = wv;
    } else {
        unsigned* o32 = (unsigned*)out16;
        const int2* inv2 = (const int2*)inv;
#pragma unroll
        for (int t = 0; t < 8; t++) {
            int c = threadIdx.x + t * 256;
            int2 ij = inv2[c];
            o32[c] = pack_bf2(rowbuf[ij.x], rowbuf[ij.y]);
        }
    }
}

// hidden -> Xb (bf16) + Xf8 (fp8 x64, swizzled). One block per row of 4096.
__global__ __launch_bounds__(256) void cvt_k(const float* __restrict__ x,
                                             u16* __restrict__ Xb,
                                             u8* __restrict__ Xf8) {
    int row = blockIdx.x;
    int t = threadIdx.x;                           // 16 consecutive floats per thread
    const float4* src = (const float4*)(x + (size_t)row * 4096);
    float v[16];
#pragma unroll
    for (int u = 0; u < 4; u++) {
        float4 a = src[t * 4 + u];
        v[4 * u + 0] = a.x; v[4 * u + 1] = a.y; v[4 * u + 2] = a.z; v[4 * u + 3] = a.w;
    }
    uint4 b0, b1;
    b0.x = pack_bf2(v[0], v[1]);  b0.y = pack_bf2(v[2], v[3]);
    b0.z = pack_bf2(v[4], v[5]);  b0.w = pack_bf2(v[6], v[7]);
    b1.x = pack_bf2(v[8], v[9]);  b1.y = pack_bf2(v[10], v[11]);
    b1.z = pack_bf2(v[12], v[13]); b1.w = pack_bf2(v[14], v[15]);
    uint4* ob = (uint4*)(Xb + (size_t)row * 4096);
    ob[t * 2] = b0;
    ob[t * 2 + 1] = b1;
    uint4 w8;
    w8.x = pack_fp8x4(v[0] * FP8_SCALE, v[1] * FP8_SCALE, v[2] * FP8_SCALE, v[3] * FP8_SCALE);
    w8.y = pack_fp8x4(v[4] * FP8_SCALE, v[5] * FP8_SCALE, v[6] * FP8_SCALE, v[7] * FP8_SCALE);
    w8.z = pack_fp8x4(v[8] * FP8_SCALE, v[9] * FP8_SCALE, v[10] * FP8_SCALE, v[11] * FP8_SCALE);
    w8.w = pack_fp8x4(v[12] * FP8_SCALE, v[13] * FP8_SCALE, v[14] * FP8_SCALE, v[15] * FP8_SCALE);
    int tb = (t & ~7) | ((t & 7) ^ (row & 7));
    ((uint4*)(Xf8 + (size_t)row * 4096))[tb] = w8;
}

// V transpose (sums split-K fp32 partials, kappa-permuted cols). 512 blocks: 32 x 16.
__global__ __launch_bounds__(256) void vtr_k(const float* __restrict__ Vpart,
                                             u16* __restrict__ Vt) {
    __shared__ u16 t[64][65];
    int bx = blockIdx.x;
    int s0 = (bx & 31) * 64, c0 = (bx >> 5) * 64;
    int x = threadIdx.x & 63, y4 = threadIdx.x >> 6;
    const float* Vp0 = Vpart;
    const float* Vp1 = Vpart + (size_t)2048 * 1024;
    for (int i = 0; i < 16; i++) {
        int r = y4 * 16 + i;
        size_t idx = (size_t)(s0 + r) * 1024 + c0 + x;
        t[r][x] = f2bf(Vp0[idx] + Vp1[idx]);
    }
    __syncthreads();
    for (int i = 0; i < 16; i++) {
        int r = y4 * 16 + i;
        int xk = 4 * (x & 15) + (x >> 4);  // kappa permutation within 64-key tile
        Vt[(size_t)(c0 + r) * 2048 + s0 + xk] = t[x][r];
    }
}

// ---------------- merged QKV GEMM: R2 structure + depth-2 counted-vmcnt pipeline ----------------
// 256 threads, 4 waves (2M x 2N, wave tile 64x64), 128x128 tiles, LDS 2 x 32KB dbuf (64 KB
// dynamic -> 2 blocks/CU). 8 async_copy16/thread/tile -> steady vmcnt(8), peel 8 -> 0.
// blocks x<40: Q,K via MX-fp8 (BK=128B, 32 tiles) + fused RoPE epilogue.
// blocks x in [40,56): V via bf16 (BK=64, 2-way split-K, 32 tiles), fp32 partials.

#define QKV_BAR() asm volatile("s_barrier" ::: "memory")

#define QK_STAGE(bufi, kt) do {                                                   \
    u8* la_ = S8 + (bufi) * 32768 + w * 4096;                                     \
    u8* lb_ = la_ + 16384;                                                        \
    const int k0_ = (kt) * 128;                                                   \
    _Pragma("unroll")                                                             \
    for (int t_ = 0; t_ < 4; t_++)                                                \
        async_copy16(AgQ + (size_t)t_ * 8 * 4096 + k0_, la_ + t_ * 1024);         \
    _Pragma("unroll")                                                             \
    for (int t_ = 0; t_ < 4; t_++)                                                \
        async_copy16(BgQ + (size_t)t_ * 8 * 4096 + k0_, lb_ + t_ * 1024);         \
} while (0)

#define QK_COMPUTE(bufi) do {                                                     \
    const u8* la_ = S8 + (bufi) * 32768;                                          \
    const u8* lb_ = la_ + 16384;                                                  \
    union { i32x8 v8; i32x4 v4[2]; } u_;                                          \
    i32x8 bfv[4], af0, af1;                                                       \
    _Pragma("unroll")                                                             \
    for (int j_ = 0; j_ < 4; j_++) {                                              \
        const int r_ = (wn + j_ * 16 + l16) * 128;                                \
        u_.v4[0] = *(const i32x4*)&lb_[r_ + s0b];                                 \
        u_.v4[1] = *(const i32x4*)&lb_[r_ + s1b];                                 \
        bfv[j_] = u_.v8;                                                          \
    }                                                                             \
    { const int r_ = (wm + l16) * 128;                                            \
      u_.v4[0] = *(const i32x4*)&la_[r_ + s0b];                                   \
      u_.v4[1] = *(const i32x4*)&la_[r_ + s1b]; af0 = u_.v8; }                    \
    { const int r_ = (wm + 16 + l16) * 128;                                       \
      u_.v4[0] = *(const i32x4*)&la_[r_ + s0b];                                   \
      u_.v4[1] = *(const i32x4*)&la_[r_ + s1b]; af1 = u_.v8; }                    \
    asm volatile("s_waitcnt lgkmcnt(0)" ::: "memory");                            \
    __builtin_amdgcn_sched_barrier(0);                                            \
    __builtin_amdgcn_s_setprio(1);                                                \
    _Pragma("unroll")                                                             \
    for (int j_ = 0; j_ < 4; j_++) {                                              \
        acc[0][j_] = __builtin_amdgcn_mfma_scale_f32_16x16x128_f8f6f4(af0, bfv[j_], acc[0][j_], 0, 0, 0, 0x7F7F7F7F, 0, 0x7F7F7F7F); \
        acc[1][j_] = __builtin_amdgcn_mfma_scale_f32_16x16x128_f8f6f4(af1, bfv[j_], acc[1][j_], 0, 0, 0, 0x7F7F7F7F, 0, 0x7F7F7F7F); \
    }                                                                             \
    __builtin_amdgcn_s_setprio(0);                                                \
    { const int r_ = (wm + 32 + l16) * 128;                                       \
      u_.v4[0] = *(const i32x4*)&la_[r_ + s0b];                                   \
      u_.v4[1] = *(const i32x4*)&la_[r_ + s1b]; af0 = u_.v8; }                    \
    { const int r_ = (wm + 48 + l16) * 128;                                       \
      u_.v4[0] = *(const i32x4*)&la_[r_ + s0b];                                   \
      u_.v4[1] = *(const i32x4*)&la_[r_ + s1b]; af1 = u_.v8; }                    \
    asm volatile("s_waitcnt lgkmcnt(0)" ::: "memory");                            \
    __builtin_amdgcn_sched_barrier(0);                                            \
    __builtin_amdgcn_s_setprio(1);                                                \
    _Pragma("unroll")                                                             \
    for (int j_ = 0; j_ < 4; j_++) {                                              \
        acc[2][j_] = __builtin_amdgcn_mfma_scale_f32_16x16x128_f8f6f4(af0, bfv[j_], acc[2][j_], 0, 0, 0, 0x7F7F7F7F, 0, 0x7F7F7F7F); \
        acc[3][j_] = __builtin_amdgcn_mfma_scale_f32_16x16x128_f8f6f4(af1, bfv[j_], acc[3][j_], 0, 0, 0, 0x7F7F7F7F, 0, 0x7F7F7F7F); \
    }                                                                             \
    __builtin_amdgcn_s_setprio(0);                                                \
} while (0)

#define V_STAGE(bufi, kt) do {                                                    \
    u16* a0_ = (u16*)(S8 + (bufi) * 32768);                                       \
    u16* a1_ = a0_ + 4096;                                                        \
    u16* b0_ = a0_ + 8192;                                                        \
    u16* b1_ = a0_ + 12288;                                                       \
    const int k0_ = (kt) * 64;                                                    \
    async_copy16(AgV + k0_,                          a0_ + w * 512);              \
    async_copy16(AgV + (size_t)64 * 4096 + k0_,      a0_ + (w + 4) * 512);        \
    async_copy16(AgV + k0_ + 32,                     a1_ + w * 512);              \
    async_copy16(AgV + (size_t)64 * 4096 + k0_ + 32, a1_ + (w + 4) * 512);        \
    async_copy16(BgV + k0_,                          b0_ + w * 512);              \
    async_copy16(BgV + (size_t)64 * 4096 + k0_,      b0_ + (w + 4) * 512);        \
    async_copy16(BgV + k0_ + 32,                     b1_ + w * 512);              \
    async_copy16(BgV + (size_t)64 * 4096 + k0_ + 32, b1_ + (w + 4) * 512);        \
} while (0)

#define V_COMPUTE(bufi) do {                                                      \
    const u16* base_ = (const u16*)(S8 + (bufi) * 32768);                         \
    _Pragma("unroll")                                                             \
    for (int kk_ = 0; kk_ < 2; kk_++) {                                           \
        const u16* la_ = base_ + kk_ * 4096;                                      \
        const u16* lb_ = base_ + 8192 + kk_ * 4096;                               \
        bf16x8 af[4], bfv[4];                                                     \
        _Pragma("unroll")                                                         \
        for (int i_ = 0; i_ < 4; i_++)                                            \
            af[i_] = *(const bf16x8*)&la_[(wm + i_ * 16 + l16) * 32 + quad * 8];  \
        _Pragma("unroll")                                                         \
        for (int j_ = 0; j_ < 4; j_++)                                            \
            bfv[j_] = *(const bf16x8*)&lb_[(wn + j_ * 16 + l16) * 32 + quad * 8]; \
        asm volatile("s_waitcnt lgkmcnt(0)" ::: "memory");                        \
        __builtin_amdgcn_sched_barrier(0);                                        \
        __builtin_amdgcn_s_setprio(1);                                            \
        _Pragma("unroll")                                                         \
        for (int i_ = 0; i_ < 4; i_++)                                            \
            _Pragma("unroll")                                                     \
            for (int j_ = 0; j_ < 4; j_++)                                        \
                acc[i_][j_] = __builtin_amdgcn_mfma_f32_16x16x32_bf16(af[i_], bfv[j_], acc[i_][j_], 0, 0, 0); \
        __builtin_amdgcn_s_setprio(0);                                            \
    }                                                                             \
} while (0)

__global__ __launch_bounds__(256, 2) void gemm_qkv_k(const u8* __restrict__ Xf8,
                                                     const u16* __restrict__ Xb,
                                                     const u8* __restrict__ Wqk,
                                                     const u16* __restrict__ Wv,
                                                     u16* __restrict__ QKV,
                                                     float* __restrict__ Vpart,
                                                     const float* __restrict__ cosv,
                                                     const float* __restrict__ sinv) {
    extern __shared__ u8 S8[];                 // 2 * 32768 = 64 KB
    const int tid = threadIdx.x;
    const int w = tid >> 6, lane = tid & 63;
    const int quad = lane >> 4, l16 = lane & 15;
    const int bm0 = blockIdx.y * 128;
    const int wm = (w >> 1) * 64, wn = (w & 1) * 64;
    const int swz = l16 & 7;                   // fragment row & 7
    const int s0b = ((quad * 2) ^ swz) * 16;   // fp8 16B-slot byte offsets
    const int s1b = ((quad * 2 + 1) ^ swz) * 16;

    if (blockIdx.x < 40) {
        // ---------------- Q,K MX-fp8 path ----------------
        const int bn0 = blockIdx.x * 128;
        const u8* AgQ = Xf8 + (size_t)(bm0 + w * 32 + (lane >> 3)) * 4096 + (lane & 7) * 16;
        const u8* BgQ = Wqk + (size_t)(bn0 + w * 32 + (lane >> 3)) * 4096 + (lane & 7) * 16;
        f32x4 acc[4][4] = {};

        QK_STAGE(0, 0);
        QK_STAGE(1, 1);
        asm volatile("s_waitcnt vmcnt(8)" ::: "memory");   // tile 0 landed
        QKV_BAR();
        int cur = 0;
        for (int t = 0; t < 30; ++t) {
            QK_COMPUTE(cur);
            QKV_BAR();                                     // everyone done reading buf[cur]
            QK_STAGE(cur, t + 2);
            asm volatile("s_waitcnt vmcnt(8)" ::: "memory");  // tile t+1 landed
            QKV_BAR();
            cur ^= 1;
        }
        QK_COMPUTE(0);                                     // tile 30
        asm volatile("s_waitcnt vmcnt(0)" ::: "memory");   // tile 31 landed
        QKV_BAR();
        QK_COMPUTE(1);                                     // tile 31

        // fused RoPE epilogue: with the P column permutation, lane's cols hold
        //   j even -> head-dim d1, j odd -> head-dim d1+64 (same lane, same rows).
        // Q additionally folds log2(e) so attn can use exp2 directly:
        //   0.1275174 = (1/sqrt(128)) * log2(e)
        const float qsc = (bn0 < 4096) ? 0.1275174f : 1.0f;
        const int hb = (wn ? 32 : 0) + l16;
#pragma unroll
        for (int i = 0; i < 4; i++) {
            const int row = bm0 + wm + i * 16 + quad * 4;
#pragma unroll
            for (int jp = 0; jp < 2; jp++) {       // pair groups (j=0,1) and (j=2,3)
                const int d1 = hb + jp * 16;
                const int ce = bn0 + wn + jp * 32 + l16;
#pragma unroll
                for (int r = 0; r < 4; r++) {
                    const int s = row + r;
                    const float c  = cosv[s * 128 + d1];
                    const float sn = sinv[s * 128 + d1];
                    const float x1 = acc[i][jp * 2][r]     * FP8_UNSCALE;
                    const float x2 = acc[i][jp * 2 + 1][r] * FP8_UNSCALE;
                    QKV[(size_t)s * 6144 + ce]      = f2bf((x1 * c - x2 * sn) * qsc);
                    QKV[(size_t)s * 6144 + ce + 16] = f2bf((x2 * c + x1 * sn) * qsc);
                }
            }
        }
    } else {
        // ---------------- V bf16 path (2-way split-K) ----------------
        const int vx = blockIdx.x - 40;        // 16 slots: 8 n-tiles x 2 k-slices
        const int bn0 = (vx & 7) * 128;
        const int kslice = vx >> 3;
        const int kb = kslice * 2048;
        const int r0 = w * 16 + (lane >> 2);
        const int c0 = (lane & 3) * 8;
        const u16* AgV = Xb + (size_t)(bm0 + r0) * 4096 + kb + c0;
        const u16* BgV = Wv + (size_t)(bn0 + r0) * 4096 + kb + c0;
        f32x4 acc[4][4] = {};

        V_STAGE(0, 0);
        V_STAGE(1, 1);
        asm volatile("s_waitcnt vmcnt(8)" ::: "memory");
        QKV_BAR();
        int cur = 0;
        for (int t = 0; t < 30; ++t) {
            V_COMPUTE(cur);
            QKV_BAR();
            V_STAGE(cur, t + 2);
            asm volatile("s_waitcnt vmcnt(8)" ::: "memory");
            QKV_BAR();
            cur ^= 1;
        }
        V_COMPUTE(0);                                      // tile 30
        asm volatile("s_waitcnt vmcnt(0)" ::: "memory");   // tile 31 landed
        QKV_BAR();
        V_COMPUTE(1);                                      // tile 31

        float* Vp = Vpart + (size_t)kslice * 2048 * 1024;
#pragma unroll
        for (int i = 0; i < 4; i++) {
            const int row = bm0 + wm + i * 16 + quad * 4;
#pragma unroll
            for (int j = 0; j < 4; j++) {
                const int col = bn0 + wn + j * 16 + l16;
#pragma unroll
                for (int r = 0; r < 4; r++)
                    Vp[(size_t)(row + r) * 1024 + col] = acc[i][j][r];
            }
        }
    }
}

// ---------------- O-projection GEMM: single-pass K=4096, depth-3 counted-vmcnt pipeline --------
// BM=256, BN=128, BK=64. 512 thr (8 waves, 4Mx2N, 64x64/wave). LDS: 3 x 48KB buffers (dynamic).
// Stage uses inverse-swizzled global source (linear LDS dest); ds_read applies slot^=(row&7)
// -> conflict-free b128 batches. vmcnt(12) steady state (2 tiles in flight), peel 12->6->0.
// Direct fp32 store to d_out: no split-K, no atomics, no memset, no reduce.

#define GO_STAGE(bufi, kt) do {                                                   \
    u16* la_ = S + (bufi) * 24576;                                                \
    u16* lb_ = la_ + 16384;                                                       \
    const int k0_ = (kt) * 64;                                                    \
    _Pragma("unroll")                                                             \
    for (int u = 0; u < 4; u++)                                                   \
        async_copy16(Asrc + (size_t)u * 64 * 4096 + k0_, la_ + u * 4096 + sdst);  \
    _Pragma("unroll")                                                             \
    for (int u = 0; u < 2; u++)                                                   \
        async_copy16(Bsrc + (size_t)u * 64 * 4096 + k0_, lb_ + u * 4096 + sdst);  \
} while (0)

#define GO_COMPUTE(bufi) do {                                                     \
    const u16* la_ = S + (bufi) * 24576;                                          \
    const u16* lb_ = la_ + 16384;                                                 \
    bf16x8 bfr[4][2], afr[2][2];                                                  \
    _Pragma("unroll")                                                             \
    for (int j = 0; j < 4; j++) {                                                 \
        const int rb_ = (wn + j * 16 + l16) * 64;                                 \
        bfr[j][0] = *(const bf16x8*)&lb_[rb_ + o0];                               \
        bfr[j][1] = *(const bf16x8*)&lb_[rb_ + o1];                               \
    }                                                                             \
    _Pragma("unroll")                                                             \
    for (int i = 0; i < 2; i++) {                                                 \
        const int ra_ = (wm + i * 16 + l16) * 64;                                 \
        afr[i][0] = *(const bf16x8*)&la_[ra_ + o0];                               \
        afr[i][1] = *(const bf16x8*)&la_[ra_ + o1];                               \
    }                                                                             \
    asm volatile("s_waitcnt lgkmcnt(0)" ::: "memory");                            \
    __builtin_amdgcn_sched_barrier(0);                                            \
    __builtin_amdgcn_s_setprio(1);                                                \
    _Pragma("unroll")                                                             \
    for (int i = 0; i < 2; i++)                                                   \
        _Pragma("unroll")                                                         \
        for (int j = 0; j < 4; j++) {                                             \
            acc[i][j] = __builtin_amdgcn_mfma_f32_16x16x32_bf16(afr[i][0], bfr[j][0], acc[i][j], 0, 0, 0); \
            acc[i][j] = __builtin_amdgcn_mfma_f32_16x16x32_bf16(afr[i][1], bfr[j][1], acc[i][j], 0, 0, 0); \
        }                                                                         \
    __builtin_amdgcn_s_setprio(0);                                                \
    _Pragma("unroll")                                                             \
    for (int i = 0; i < 2; i++) {                                                 \
        const int ra_ = (wm + (i + 2) * 16 + l16) * 64;                           \
        afr[i][0] = *(const bf16x8*)&la_[ra_ + o0];                               \
        afr[i][1] = *(const bf16x8*)&la_[ra_ + o1];                               \
    }                                                                             \
    asm volatile("s_waitcnt lgkmcnt(0)" ::: "memory");                            \
    __builtin_amdgcn_sched_barrier(0);                                            \
    __builtin_amdgcn_s_setprio(1);                                                \
    _Pragma("unroll")                                                             \
    for (int i = 0; i < 2; i++)                                                   \
        _Pragma("unroll")                                                         \
        for (int j = 0; j < 4; j++) {                                             \
            acc[i + 2][j] = __builtin_amdgcn_mfma_f32_16x16x32_bf16(afr[i][0], bfr[j][0], acc[i + 2][j], 0, 0, 0); \
            acc[i + 2][j] = __builtin_amdgcn_mfma_f32_16x16x32_bf16(afr[i][1], bfr[j][1], acc[i + 2][j], 0, 0, 0); \
        }                                                                         \
    __builtin_amdgcn_s_setprio(0);                                                \
} while (0)

#define GO_BAR() asm volatile("s_barrier" ::: "memory")

__global__ __launch_bounds__(512, 2) void gemm_o_k(const u16* __restrict__ A,
                                                   const u16* __restrict__ B,
                                                   float* __restrict__ Out) {
    extern __shared__ u16 S[];                 // 3 * 49152 B = 144 KB
    const int tid = threadIdx.x;
    const int w = tid >> 6, lane = tid & 63;
    const int quad = lane >> 4, l16 = lane & 15;
    // XCD-bijective swizzle over 256 blocks: each XCD gets one contiguous m-row (A-panel L2-resident)
    const int linear = blockIdx.y * 32 + blockIdx.x;
    const int wgid = (linear & 7) * 32 + (linear >> 3);
    const int bm0 = (wgid >> 5) * 256;
    const int bn0 = (wgid & 31) * 128;
    const int wm = (w >> 1) * 64;              // 4 waves along M
    const int wn = (w & 1) * 64;               // 2 waves along N
    // staging: thread -> (row = u*64 + tid>>3, col16B = (tid&7) ^ (row&7))  [inverse swizzle]
    const int sr = tid >> 3;
    const int scg = ((tid & 7) ^ (sr & 7)) * 8;
    const int sdst = tid * 8;                  // u16 units (16B/thread)
    const u16* Asrc = A + (size_t)(bm0 + sr) * 4096 + scg;
    const u16* Bsrc = B + (size_t)(bn0 + sr) * 4096 + scg;
    // fragment read swizzle: slot = ((kk<<2)|quad) ^ (row&7); row&7 == l16&7 here
    const int swz = l16 & 7;
    const int o0 = (quad ^ swz) * 8;           // u16 offset for kk=0
    const int o1 = ((4 | quad) ^ swz) * 8;     // u16 offset for kk=1

    f32x4 acc[4][4] = {};

    GO_STAGE(0, 0);
    GO_STAGE(1, 1);
    GO_STAGE(2, 2);
    asm volatile("s_waitcnt vmcnt(12)" ::: "memory");   // tile 0 landed
    GO_BAR();

    int cur = 0;
    for (int t = 0; t < 61; ++t) {
        GO_COMPUTE(cur);
        GO_BAR();                                        // all waves done reading buf[cur]
        GO_STAGE(cur, t + 3);
        asm volatile("s_waitcnt vmcnt(12)" ::: "memory"); // tile t+1 landed (t+2,t+3 in flight)
        GO_BAR();
        cur = (cur == 2) ? 0 : cur + 1;
    }
    // t = 61 (buf 1): tile 63's 6 loads may still be in flight
    GO_COMPUTE(1);
    asm volatile("s_waitcnt vmcnt(6)" ::: "memory");      // tile 62 landed
    GO_BAR();
    // t = 62 (buf 2)
    GO_COMPUTE(2);
    asm volatile("s_waitcnt vmcnt(0)" ::: "memory");      // tile 63 landed
    GO_BAR();
    // t = 63 (buf 0)
    GO_COMPUTE(0);

#pragma unroll
    for (int i = 0; i < 4; i++) {
        const int row = bm0 + wm + i * 16 + quad * 4;
#pragma unroll
        for (int j = 0; j < 4; j++) {
            const int col = bn0 + wn + j * 16 + l16;
#pragma unroll
            for (int r = 0; r < 4; r++)
                Out[(size_t)(row + r) * 4096 + col] = acc[i][j][r];
        }
    }
}

// ---------------- fused flash attention (GQA, causal, no-max softmax) ----------------
// 8 waves x 16 q-rows (512 thr). Grid (32 heads, 8): each block processes the q-tile
// PAIR (15-y, y) sequentially -> uniform 34 k-tiles/block, 256 blocks = 1/CU, no tail.
// 2 waves/SIMD minimum -> softmax VALU of one wave overlaps MFMA of the other.
// Q carries log2(e) in its scale; softmax uses exp2 directly.

__global__ __launch_bounds__(512) void attn_k(const u16* __restrict__ Qb,
                                              const u16* __restrict__ Kb,
                                              const u16* __restrict__ Vt,
                                              u16* __restrict__ Ob,
                                              int qstride, int kstride) {
    __shared__ u16 ldsK[4 * 64 * 32];   // [kk][key][hd32]
    __shared__ u16 ldsV[2 * 128 * 32];  // [ks][d][kappa32]
    __shared__ u16 ldsP[8][16 * 72];    // per-wave [m 16][kappa 64 + pad 8]
    const int h = blockIdx.x;
    const int kvh = h >> 2;
    const int tid = threadIdx.x;
    const int w = tid >> 6, lane = tid & 63;
    const int quad = lane >> 4, l16 = lane & 15;

    // staging chunk assignment: 32 chunks (16 K + 16 V), 4 per wave
    const u16* kp0[2]; const u16* vp0[2];
    u16* ldk[2]; u16* ldv[2];
#pragma unroll
    for (int t = 0; t < 2; t++) {
        int wl = w + t * 8;
        int kk = wl >> 2, part = wl & 3;
        kp0[t] = Kb + (size_t)(part * 16 + (lane >> 2)) * kstride + kvh * 128 + kk * 32 + (lane & 3) * 8;
        int ks2 = wl >> 3, p2 = wl & 7;
        vp0[t] = Vt + (size_t)(kvh * 128 + p2 * 16 + (lane >> 2)) * 2048 + ks2 * 32 + (lane & 3) * 8;
        ldk[t] = ldsK + wl * 512;
        ldv[t] = ldsV + wl * 512;
    }

#pragma unroll
    for (int ph = 0; ph < 2; ph++) {
        const int qt = ph == 0 ? (15 - (int)blockIdx.y) : (int)blockIdx.y;
        const int q0 = qt * 128;
        const int wrow = q0 + w * 16;

        bf16x8 qf[4];
#pragma unroll
        for (int kk = 0; kk < 4; kk++)
            qf[kk] = *(const bf16x8*)&Qb[(size_t)(wrow + l16) * qstride +
                                         h * 128 + kk * 32 + quad * 8];

        const u16* kp[2]; const u16* vp[2];
        kp[0] = kp0[0]; kp[1] = kp0[1];
        vp[0] = vp0[0]; vp[1] = vp0[1];

        f32x4 acc_o[8] = {};
        float lrow[4] = {};

        const int nk = 2 * (qt + 1);
        for (int kn = 0; kn < nk; kn++) {
            const int g0 = kn * 64;
            async_copy16(kp[0], ldk[0]);
            async_copy16(kp[1], ldk[1]);
            async_copy16(vp[0], ldv[0]);
            async_copy16(vp[1], ldv[1]);
            kp[0] += (size_t)64 * kstride; kp[1] += (size_t)64 * kstride;
            vp[0] += 64; vp[1] += 64;
            __syncthreads();

            if (g0 <= wrow + 15) {
                f32x4 accs[4] = {};
#pragma unroll
                for (int kk = 0; kk < 4; kk++) {
                    bf16x8 bfrag[4];
#pragma unroll
                    for (int ni = 0; ni < 4; ni++)
                        bfrag[ni] = *(const bf16x8*)&ldsK[kk * 2048 + (ni * 16 + l16) * 32 + quad * 8];
                    __builtin_amdgcn_s_setprio(1);
#pragma unroll
                    for (int ni = 0; ni < 4; ni++)
                        accs[ni] = __builtin_amdgcn_mfma_f32_16x16x32_bf16(
                            qf[kk], bfrag[ni], accs[ni], 0, 0, 0);
                    __builtin_amdgcn_s_setprio(0);
                }
                const bool diag = (g0 + 63 > wrow);
                int kidx[4];
#pragma unroll
                for (int ni = 0; ni < 4; ni++) kidx[ni] = g0 + ni * 16 + l16;
#pragma unroll
                for (int r = 0; r < 4; r++) {
                    const int qrow = wrow + quad * 4 + r;
                    float p[4];
#pragma unroll
                    for (int ni = 0; ni < 4; ni++) {
                        float s = accs[ni][r];
                        if (diag && (kidx[ni] > qrow)) s = -1e30f;
                        p[ni] = __builtin_amdgcn_exp2f(s);
                    }
                    lrow[r] += (p[0] + p[1]) + (p[2] + p[3]);
                    uint2 pk;
                    pk.x = pack_bf2(p[0], p[1]);
                    pk.y = pack_bf2(p[2], p[3]);
                    *(uint2*)&ldsP[w][(quad * 4 + r) * 72 + l16 * 4] = pk;
                }
#pragma unroll
                for (int ks = 0; ks < 2; ks++) {
                    bf16x8 pa = *(const bf16x8*)&ldsP[w][l16 * 72 + ks * 32 + quad * 8];
                    __builtin_amdgcn_s_setprio(1);
#pragma unroll
                    for (int oj = 0; oj < 8; oj++) {
                        bf16x8 vb = *(const bf16x8*)&ldsV[ks * 4096 + (oj * 16 + l16) * 32 + quad * 8];
                        acc_o[oj] = __builtin_amdgcn_mfma_f32_16x16x32_bf16(
                            pa, vb, acc_o[oj], 0, 0, 0);
                    }
                    __builtin_amdgcn_s_setprio(0);
                }
            }
            __syncthreads();
        }

#pragma unroll
        for (int r = 0; r < 4; r++) {
            float l = lrow[r];
            l += __shfl_xor(l, 1);
            l += __shfl_xor(l, 2);
            l += __shfl_xor(l, 4);
            l += __shfl_xor(l, 8);
            const float inv = 1.0f / l;
            const int qrow = wrow + quad * 4 + r;
#pragma unroll
            for (int oj = 0; oj < 8; oj++)
                Ob[(size_t)qrow * 4096 + h * 128 + oj * 16 + l16] =
                    f2bf(acc_o[oj][r] * inv);
        }
    }
}

// ---------------- launch ----------------

extern "C" void kernel_launch(void* const* d_in, const int* in_sizes, int n_in,
                              void* d_out, int out_size, void* d_ws, size_t ws_size,
                              hipStream_t stream) {
    (void)in_sizes; (void)n_in; (void)out_size; (void)ws_size;
    const float* hidden = (const float*)d_in[0];
    const float* Wq = (const float*)d_in[1];
    const float* Wk = (const float*)d_in[2];
    const float* Wv = (const float*)d_in[3];
    const float* Wo = (const float*)d_in[4];
    const float* cosv = (const float*)d_in[5];
    const float* sinv = (const float*)d_in[6];
    const int* qoc = (const int*)d_in[8];
    const int* qor = (const int*)d_in[9];
    const int* koc = (const int*)d_in[10];
    const int* kor = (const int*)d_in[11];
    const int* voc = (const int*)d_in[12];
    const int* vor = (const int*)d_in[13];
    const int* ooc = (const int*)d_in[14];
    const int* oor = (const int*)d_in[15];

    char* ws = (char*)d_ws;
    size_t off = 0;
    // persistent across the whole pipeline:
    int* invq = (int*)(ws + off); off += 16384;
    int* invk = (int*)(ws + off); off += 16384;
    int* invv = (int*)(ws + off); off += 16384;
    int* invo = (int*)(ws + off); off += 16384;
    u16* Wop   = (u16*)(ws + off); off += (size_t)4096 * 4096 * 2;   // 33.5 MB (live at O-proj)
    u16* Xb    = (u16*)(ws + off); off += (size_t)2048 * 4096 * 2;   // 16.8 MB (live as Attb)
    u8*  Wqkf8 = (u8*)(ws + off);  off += (size_t)5120 * 4096;       // 21.0 MB
    u16* Wvp   = (u16*)(ws + off); off += (size_t)1024 * 4096 * 2;   //  8.4 MB
    u8*  Xf8   = (u8*)(ws + off);  off += (size_t)2048 * 4096;       //  8.4 MB
    u16* QKVb  = (u16*)(ws + off); off += (size_t)2048 * 6144 * 2;   // 25.2 MB
    u16* Vtb   = (u16*)(ws + off); off += (size_t)1024 * 2048 * 2;   //  4.2 MB
    float* Vpart = (float*)(ws + off); off += (size_t)2 * 2048 * 1024 * 4;  // 16.8 MB
    u16* Attb  = Xb;   // Xb dead after gemm_qkv_k; reuse for attention output

    inv4_k<<<64, 256, 0, stream>>>(qoc, koc, voc, ooc, invq, invk, invv, invo);
    permw4_k<<<10240, 256, 0, stream>>>(Wq, Wk, Wv, Wo, qor, kor, vor, oor,
                                        invq, invk, invv, invo, Wqkf8, Wvp, Wop);
    cvt_k<<<2048, 256, 0, stream>>>(hidden, Xb, Xf8);

    // QKV: Q,K via MX-fp8 (+fused RoPE/scale/log2e) + V via bf16 split-K2 -> QKVb + Vpart
    gemm_qkv_k<<<dim3(56, 16), 256, 65536, stream>>>(Xf8, Xb, Wqkf8, Wvp, QKVb, Vpart,
                                                     cosv, sinv);

    // Vt build (sums split-K partials, kappa permutation)
    vtr_k<<<512, 256, 0, stream>>>(Vpart, Vtb);

    // attention -> Attb [2048][4096]  (reuses Xb storage)
    attn_k<<<dim3(32, 8), 512, 0, stream>>>(QKVb, QKVb + 4096, Vtb, Attb, 6144, 6144);

    // O-projection: single-pass pipelined bf16 GEMM, direct fp32 store
    gemm_o_k<<<dim3(32, 8), 512, 147456, stream>>>(Attb, Wop, (float*)d_out);
}

// Round 6
// 451.020 us; speedup vs baseline: 1.1041x; 1.0376x over previous
//
#include <hip/hip_runtime.h>

typedef unsigned short u16;
typedef unsigned char u8;
typedef __bf16 bf16x8 __attribute__((ext_vector_type(8)));
typedef float f32x4 __attribute__((ext_vector_type(4)));
typedef int i32x4 __attribute__((ext_vector_type(4)));
typedef int i32x8 __attribute__((ext_vector_type(8)));

__device__ __forceinline__ u16 f2bf(float f) {
    unsigned u = __float_as_uint(f);
    unsigned r = (u + 0x7fffu + ((u >> 16) & 1u)) >> 16;
    return (u16)r;
}
__device__ __forceinline__ float bf2f(u16 h) {
    return __uint_as_float(((unsigned)h) << 16);
}
// pack two floats to bf16x2 (lo in low half), round-half-up, single v_perm
__device__ __forceinline__ unsigned pack_bf2(float lo, float hi) {
    unsigned a = __float_as_uint(hi) + 0x8000u;
    unsigned b = __float_as_uint(lo) + 0x8000u;
    return __builtin_amdgcn_perm(a, b, 0x07060302u);
}
// pack 4 floats to 4 fp8 e4m3 bytes
__device__ __forceinline__ unsigned pack_fp8x4(float a, float b, float c, float d) {
    unsigned w = __builtin_amdgcn_cvt_pk_fp8_f32(a, b, 0, false);
    w = __builtin_amdgcn_cvt_pk_fp8_f32(c, d, w, true);
    return w;
}
__device__ __forceinline__ void async_copy16(const void* g, void* l) {
    __builtin_amdgcn_global_load_lds((__attribute__((address_space(1))) void*)(void*)g,
                                     (__attribute__((address_space(3))) void*)l, 16, 0, 0);
}

#define FP8_SCALE 64.0f          // pre-scale before e4m3 quant (avoids subnormals)
#define FP8_UNSCALE (1.0f / 4096.0f)  // (1/64)^2 applied at GEMM epilogue

// ---------------- prep kernels ----------------

__global__ void inv4_k(const int* __restrict__ q, const int* __restrict__ k,
                       const int* __restrict__ v, const int* __restrict__ o,
                       int* __restrict__ invq, int* __restrict__ invk,
                       int* __restrict__ invv, int* __restrict__ invo) {
    int i = blockIdx.x * 256 + threadIdx.x;   // grid 64 -> 16384 = 4*4096
    int a = i >> 12, j = i & 4095;
    const int* p = a == 0 ? q : a == 1 ? k : a == 2 ? v : o;
    int* inv = a == 0 ? invq : a == 1 ? invk : a == 2 ? invv : invo;
    inv[p[j]] = j;
}

// Weight permutations. Q,K rows -> fp8 (x64, XOR-swizzled 16B blocks); V,O rows -> bf16.
// Q,K additionally get a head-dim COLUMN permutation P (applied by selecting permuted
// weight rows) so RoPE pairs (d, d+64) land in adjacent j-fragments of one lane in the
// MFMA C-layout.  QK^T is invariant: Q and K share the same P.
//   P[hd] = (hd&15) | ((b&1)<<6) | ((b&2)<<3) | ((hd&64)>>1),  b = hd>>4
__global__ __launch_bounds__(256) void permw4_k(
    const float* __restrict__ Wq, const float* __restrict__ Wk,
    const float* __restrict__ Wv, const float* __restrict__ Wo,
    const int* __restrict__ qor, const int* __restrict__ kor,
    const int* __restrict__ vor, const int* __restrict__ oor,
    const int* __restrict__ invq, const int* __restrict__ invk,
    const int* __restrict__ invv, const int* __restrict__ invo,
    u8* __restrict__ Wqkf8, u16* __restrict__ Wvp, u16* __restrict__ Wop) {
    __shared__ float rowbuf[4096];
    int j = blockIdx.x;
    const float* W; const int* rp; const int* inv; int row; int f8;
    u8* out8 = nullptr; u16* out16 = nullptr;
    if (j < 4096)      { W = Wq; rp = qor; inv = invq; row = j;        out8 = Wqkf8 + (size_t)j * 4096; f8 = 1; }
    else if (j < 5120) { W = Wk; rp = kor; inv = invk; row = j - 4096; out8 = Wqkf8 + (size_t)j * 4096; f8 = 1; }
    else if (j < 6144) { W = Wv; rp = vor; inv = invv; row = j - 5120; out16 = Wvp + (size_t)(j - 5120) * 4096; f8 = 0; }
    else               { W = Wo; rp = oor; inv = invo; row = j - 6144; out16 = Wop + (size_t)(j - 6144) * 4096; f8 = 0; }
    if (f8) {   // head-dim column permutation for Q,K (RoPE pairing)
        int hd = row & 127, b = hd >> 4;
        row = (row & ~127) | ((hd & 15) | ((b & 1) << 6) | ((b & 2) << 3) | ((hd & 64) >> 1));
    }
    const float4* wr4 = (const float4*)(W + (size_t)rp[row] * 4096);
#pragma unroll
    for (int t = 0; t < 4; t++)
        ((float4*)rowbuf)[threadIdx.x + t * 256] = wr4[threadIdx.x + t * 256];
    __syncthreads();
    if (f8) {
        int t = threadIdx.x;                       // one 16B block per thread
        const int4* inv4p = (const int4*)inv;
        float v[16];
#pragma unroll
        for (int u = 0; u < 4; u++) {
            int4 ix = inv4p[t * 4 + u];
            v[4 * u + 0] = rowbuf[ix.x] * FP8_SCALE;
            v[4 * u + 1] = rowbuf[ix.y] * FP8_SCALE;
            v[4 * u + 2] = rowbuf[ix.z] * FP8_SCALE;
            v[4 * u + 3] = rowbuf[ix.w] * FP8_SCALE;
        }
        uint4 wv;
        wv.x = pack_fp8x4(v[0], v[1], v[2], v[3]);
        wv.y = pack_fp8x4(v[4], v[5], v[6], v[7]);
        wv.z = pack_fp8x4(v[8], v[9], v[10], v[11]);
        wv.w = pack_fp8x4(v[12], v[13], v[14], v[15]);
        int tb = (t & ~7) | ((t & 7) ^ (j & 7));   // XOR swizzle within 128B segment
        ((uint4*)out8)[tb] = wv;
    } else {
        unsigned* o32 = (unsigned*)out16;
        const int2* inv2 = (const int2*)inv;
#pragma unroll
        for (int t = 0; t < 8; t++) {
            int c = threadIdx.x + t * 256;
            int2 ij = inv2[c];
            o32[c] = pack_bf2(rowbuf[ij.x], rowbuf[ij.y]);
        }
    }
}

// hidden -> Xb (bf16) + Xf8 (fp8 x64, swizzled). One block per row of 4096.
__global__ __launch_bounds__(256) void cvt_k(const float* __restrict__ x,
                                             u16* __restrict__ Xb,
                                             u8* __restrict__ Xf8) {
    int row = blockIdx.x;
    int t = threadIdx.x;                           // 16 consecutive floats per thread
    const float4* src = (const float4*)(x + (size_t)row * 4096);
    float v[16];
#pragma unroll
    for (int u = 0; u < 4; u++) {
        float4 a = src[t * 4 + u];
        v[4 * u + 0] = a.x; v[4 * u + 1] = a.y; v[4 * u + 2] = a.z; v[4 * u + 3] = a.w;
    }
    uint4 b0, b1;
    b0.x = pack_bf2(v[0], v[1]);  b0.y = pack_bf2(v[2], v[3]);
    b0.z = pack_bf2(v[4], v[5]);  b0.w = pack_bf2(v[6], v[7]);
    b1.x = pack_bf2(v[8], v[9]);  b1.y = pack_bf2(v[10], v[11]);
    b1.z = pack_bf2(v[12], v[13]); b1.w = pack_bf2(v[14], v[15]);
    uint4* ob = (uint4*)(Xb + (size_t)row * 4096);
    ob[t * 2] = b0;
    ob[t * 2 + 1] = b1;
    uint4 w8;
    w8.x = pack_fp8x4(v[0] * FP8_SCALE, v[1] * FP8_SCALE, v[2] * FP8_SCALE, v[3] * FP8_SCALE);
    w8.y = pack_fp8x4(v[4] * FP8_SCALE, v[5] * FP8_SCALE, v[6] * FP8_SCALE, v[7] * FP8_SCALE);
    w8.z = pack_fp8x4(v[8] * FP8_SCALE, v[9] * FP8_SCALE, v[10] * FP8_SCALE, v[11] * FP8_SCALE);
    w8.w = pack_fp8x4(v[12] * FP8_SCALE, v[13] * FP8_SCALE, v[14] * FP8_SCALE, v[15] * FP8_SCALE);
    int tb = (t & ~7) | ((t & 7) ^ (row & 7));
    ((uint4*)(Xf8 + (size_t)row * 4096))[tb] = w8;
}

// V transpose (sums split-K fp32 partials, kappa-permuted cols). 512 blocks: 32 x 16.
__global__ __launch_bounds__(256) void vtr_k(const float* __restrict__ Vpart,
                                             u16* __restrict__ Vt) {
    __shared__ u16 t[64][65];
    int bx = blockIdx.x;
    int s0 = (bx & 31) * 64, c0 = (bx >> 5) * 64;
    int x = threadIdx.x & 63, y4 = threadIdx.x >> 6;
    const float* Vp0 = Vpart;
    const float* Vp1 = Vpart + (size_t)2048 * 1024;
    for (int i = 0; i < 16; i++) {
        int r = y4 * 16 + i;
        size_t idx = (size_t)(s0 + r) * 1024 + c0 + x;
        t[r][x] = f2bf(Vp0[idx] + Vp1[idx]);
    }
    __syncthreads();
    for (int i = 0; i < 16; i++) {
        int r = y4 * 16 + i;
        int xk = 4 * (x & 15) + (x >> 4);  // kappa permutation within 64-key tile
        Vt[(size_t)(c0 + r) * 2048 + s0 + xk] = t[x][r];
    }
}

// ---------------- merged QKV GEMM: R2 structure + depth-2 counted-vmcnt pipeline ----------------
// 256 threads, 4 waves (2M x 2N, wave tile 64x64), 128x128 tiles, LDS 2 x 32KB dbuf (64 KB
// dynamic -> 2 blocks/CU). 8 async_copy16/thread/tile -> steady vmcnt(8), peel 8 -> 0.
// blocks x<40: Q,K via MX-fp8 (BK=128B, 32 tiles) + fused RoPE epilogue.
// blocks x in [40,56): V via bf16 (BK=64, 2-way split-K, 32 tiles), fp32 partials.

#define QKV_BAR() asm volatile("s_barrier" ::: "memory")

#define QK_STAGE(bufi, kt) do {                                                   \
    u8* la_ = S8 + (bufi) * 32768 + w * 4096;                                     \
    u8* lb_ = la_ + 16384;                                                        \
    const int k0_ = (kt) * 128;                                                   \
    _Pragma("unroll")                                                             \
    for (int t_ = 0; t_ < 4; t_++)                                                \
        async_copy16(AgQ + (size_t)t_ * 8 * 4096 + k0_, la_ + t_ * 1024);         \
    _Pragma("unroll")                                                             \
    for (int t_ = 0; t_ < 4; t_++)                                                \
        async_copy16(BgQ + (size_t)t_ * 8 * 4096 + k0_, lb_ + t_ * 1024);         \
} while (0)

#define QK_COMPUTE(bufi) do {                                                     \
    const u8* la_ = S8 + (bufi) * 32768;                                          \
    const u8* lb_ = la_ + 16384;                                                  \
    union { i32x8 v8; i32x4 v4[2]; } u_;                                          \
    i32x8 bfv[4], af0, af1;                                                       \
    _Pragma("unroll")                                                             \
    for (int j_ = 0; j_ < 4; j_++) {                                              \
        const int r_ = (wn + j_ * 16 + l16) * 128;                                \
        u_.v4[0] = *(const i32x4*)&lb_[r_ + s0b];                                 \
        u_.v4[1] = *(const i32x4*)&lb_[r_ + s1b];                                 \
        bfv[j_] = u_.v8;                                                          \
    }                                                                             \
    { const int r_ = (wm + l16) * 128;                                            \
      u_.v4[0] = *(const i32x4*)&la_[r_ + s0b];                                   \
      u_.v4[1] = *(const i32x4*)&la_[r_ + s1b]; af0 = u_.v8; }                    \
    { const int r_ = (wm + 16 + l16) * 128;                                       \
      u_.v4[0] = *(const i32x4*)&la_[r_ + s0b];                                   \
      u_.v4[1] = *(const i32x4*)&la_[r_ + s1b]; af1 = u_.v8; }                    \
    asm volatile("s_waitcnt lgkmcnt(0)" ::: "memory");                            \
    __builtin_amdgcn_sched_barrier(0);                                            \
    __builtin_amdgcn_s_setprio(1);                                                \
    _Pragma("unroll")                                                             \
    for (int j_ = 0; j_ < 4; j_++) {                                              \
        acc[0][j_] = __builtin_amdgcn_mfma_scale_f32_16x16x128_f8f6f4(af0, bfv[j_], acc[0][j_], 0, 0, 0, 0x7F7F7F7F, 0, 0x7F7F7F7F); \
        acc[1][j_] = __builtin_amdgcn_mfma_scale_f32_16x16x128_f8f6f4(af1, bfv[j_], acc[1][j_], 0, 0, 0, 0x7F7F7F7F, 0, 0x7F7F7F7F); \
    }                                                                             \
    __builtin_amdgcn_s_setprio(0);                                                \
    { const int r_ = (wm + 32 + l16) * 128;                                       \
      u_.v4[0] = *(const i32x4*)&la_[r_ + s0b];                                   \
      u_.v4[1] = *(const i32x4*)&la_[r_ + s1b]; af0 = u_.v8; }                    \
    { const int r_ = (wm + 48 + l16) * 128;                                       \
      u_.v4[0] = *(const i32x4*)&la_[r_ + s0b];                                   \
      u_.v4[1] = *(const i32x4*)&la_[r_ + s1b]; af1 = u_.v8; }                    \
    asm volatile("s_waitcnt lgkmcnt(0)" ::: "memory");                            \
    __builtin_amdgcn_sched_barrier(0);                                            \
    __builtin_amdgcn_s_setprio(1);                                                \
    _Pragma("unroll")                                                             \
    for (int j_ = 0; j_ < 4; j_++) {                                              \
        acc[2][j_] = __builtin_amdgcn_mfma_scale_f32_16x16x128_f8f6f4(af0, bfv[j_], acc[2][j_], 0, 0, 0, 0x7F7F7F7F, 0, 0x7F7F7F7F); \
        acc[3][j_] = __builtin_amdgcn_mfma_scale_f32_16x16x128_f8f6f4(af1, bfv[j_], acc[3][j_], 0, 0, 0, 0x7F7F7F7F, 0, 0x7F7F7F7F); \
    }                                                                             \
    __builtin_amdgcn_s_setprio(0);                                                \
} while (0)

#define V_STAGE(bufi, kt) do {                                                    \
    u16* a0_ = (u16*)(S8 + (bufi) * 32768);                                       \
    u16* a1_ = a0_ + 4096;                                                        \
    u16* b0_ = a0_ + 8192;                                                        \
    u16* b1_ = a0_ + 12288;                                                       \
    const int k0_ = (kt) * 64;                                                    \
    async_copy16(AgV + k0_,                          a0_ + w * 512);              \
    async_copy16(AgV + (size_t)64 * 4096 + k0_,      a0_ + (w + 4) * 512);        \
    async_copy16(AgV + k0_ + 32,                     a1_ + w * 512);              \
    async_copy16(AgV + (size_t)64 * 4096 + k0_ + 32, a1_ + (w + 4) * 512);        \
    async_copy16(BgV + k0_,                          b0_ + w * 512);              \
    async_copy16(BgV + (size_t)64 * 4096 + k0_,      b0_ + (w + 4) * 512);        \
    async_copy16(BgV + k0_ + 32,                     b1_ + w * 512);              \
    async_copy16(BgV + (size_t)64 * 4096 + k0_ + 32, b1_ + (w + 4) * 512);        \
} while (0)

#define V_COMPUTE(bufi) do {                                                      \
    const u16* base_ = (const u16*)(S8 + (bufi) * 32768);                         \
    _Pragma("unroll")                                                             \
    for (int kk_ = 0; kk_ < 2; kk_++) {                                           \
        const u16* la_ = base_ + kk_ * 4096;                                      \
        const u16* lb_ = base_ + 8192 + kk_ * 4096;                               \
        bf16x8 af[4], bfv[4];                                                     \
        _Pragma("unroll")                                                         \
        for (int i_ = 0; i_ < 4; i_++)                                            \
            af[i_] = *(const bf16x8*)&la_[(wm + i_ * 16 + l16) * 32 + quad * 8];  \
        _Pragma("unroll")                                                         \
        for (int j_ = 0; j_ < 4; j_++)                                            \
            bfv[j_] = *(const bf16x8*)&lb_[(wn + j_ * 16 + l16) * 32 + quad * 8]; \
        asm volatile("s_waitcnt lgkmcnt(0)" ::: "memory");                        \
        __builtin_amdgcn_sched_barrier(0);                                        \
        __builtin_amdgcn_s_setprio(1);                                            \
        _Pragma("unroll")                                                         \
        for (int i_ = 0; i_ < 4; i_++)                                            \
            _Pragma("unroll")                                                     \
            for (int j_ = 0; j_ < 4; j_++)                                        \
                acc[i_][j_] = __builtin_amdgcn_mfma_f32_16x16x32_bf16(af[i_], bfv[j_], acc[i_][j_], 0, 0, 0); \
        __builtin_amdgcn_s_setprio(0);                                            \
    }                                                                             \
} while (0)

__global__ __launch_bounds__(256, 2) void gemm_qkv_k(const u8* __restrict__ Xf8,
                                                     const u16* __restrict__ Xb,
                                                     const u8* __restrict__ Wqk,
                                                     const u16* __restrict__ Wv,
                                                     u16* __restrict__ QKV,
                                                     float* __restrict__ Vpart,
                                                     const float* __restrict__ cosv,
                                                     const float* __restrict__ sinv) {
    extern __shared__ u8 S8[];                 // 2 * 32768 = 64 KB
    const int tid = threadIdx.x;
    const int w = tid >> 6, lane = tid & 63;
    const int quad = lane >> 4, l16 = lane & 15;
    const int bm0 = blockIdx.y * 128;
    const int wm = (w >> 1) * 64, wn = (w & 1) * 64;
    const int swz = l16 & 7;                   // fragment row & 7
    const int s0b = ((quad * 2) ^ swz) * 16;   // fp8 16B-slot byte offsets
    const int s1b = ((quad * 2 + 1) ^ swz) * 16;

    if (blockIdx.x < 40) {
        // ---------------- Q,K MX-fp8 path ----------------
        const int bn0 = blockIdx.x * 128;
        const u8* AgQ = Xf8 + (size_t)(bm0 + w * 32 + (lane >> 3)) * 4096 + (lane & 7) * 16;
        const u8* BgQ = Wqk + (size_t)(bn0 + w * 32 + (lane >> 3)) * 4096 + (lane & 7) * 16;
        f32x4 acc[4][4] = {};

        QK_STAGE(0, 0);
        QK_STAGE(1, 1);
        asm volatile("s_waitcnt vmcnt(8)" ::: "memory");   // tile 0 landed
        QKV_BAR();
        int cur = 0;
        for (int t = 0; t < 30; ++t) {
            QK_COMPUTE(cur);
            QKV_BAR();                                     // everyone done reading buf[cur]
            QK_STAGE(cur, t + 2);
            asm volatile("s_waitcnt vmcnt(8)" ::: "memory");  // tile t+1 landed
            QKV_BAR();
            cur ^= 1;
        }
        QK_COMPUTE(0);                                     // tile 30
        asm volatile("s_waitcnt vmcnt(0)" ::: "memory");   // tile 31 landed
        QKV_BAR();
        QK_COMPUTE(1);                                     // tile 31

        // fused RoPE epilogue: with the P column permutation, lane's cols hold
        //   j even -> head-dim d1, j odd -> head-dim d1+64 (same lane, same rows).
        // Q additionally folds log2(e) so attn can use exp2 directly:
        //   0.1275174 = (1/sqrt(128)) * log2(e)
        const float qsc = (bn0 < 4096) ? 0.1275174f : 1.0f;
        const int hb = (wn ? 32 : 0) + l16;
#pragma unroll
        for (int i = 0; i < 4; i++) {
            const int row = bm0 + wm + i * 16 + quad * 4;
#pragma unroll
            for (int jp = 0; jp < 2; jp++) {       // pair groups (j=0,1) and (j=2,3)
                const int d1 = hb + jp * 16;
                const int ce = bn0 + wn + jp * 32 + l16;
#pragma unroll
                for (int r = 0; r < 4; r++) {
                    const int s = row + r;
                    const float c  = cosv[s * 128 + d1];
                    const float sn = sinv[s * 128 + d1];
                    const float x1 = acc[i][jp * 2][r]     * FP8_UNSCALE;
                    const float x2 = acc[i][jp * 2 + 1][r] * FP8_UNSCALE;
                    QKV[(size_t)s * 6144 + ce]      = f2bf((x1 * c - x2 * sn) * qsc);
                    QKV[(size_t)s * 6144 + ce + 16] = f2bf((x2 * c + x1 * sn) * qsc);
                }
            }
        }
    } else {
        // ---------------- V bf16 path (2-way split-K) ----------------
        const int vx = blockIdx.x - 40;        // 16 slots: 8 n-tiles x 2 k-slices
        const int bn0 = (vx & 7) * 128;
        const int kslice = vx >> 3;
        const int kb = kslice * 2048;
        const int r0 = w * 16 + (lane >> 2);
        const int c0 = (lane & 3) * 8;
        const u16* AgV = Xb + (size_t)(bm0 + r0) * 4096 + kb + c0;
        const u16* BgV = Wv + (size_t)(bn0 + r0) * 4096 + kb + c0;
        f32x4 acc[4][4] = {};

        V_STAGE(0, 0);
        V_STAGE(1, 1);
        asm volatile("s_waitcnt vmcnt(8)" ::: "memory");
        QKV_BAR();
        int cur = 0;
        for (int t = 0; t < 30; ++t) {
            V_COMPUTE(cur);
            QKV_BAR();
            V_STAGE(cur, t + 2);
            asm volatile("s_waitcnt vmcnt(8)" ::: "memory");
            QKV_BAR();
            cur ^= 1;
        }
        V_COMPUTE(0);                                      // tile 30
        asm volatile("s_waitcnt vmcnt(0)" ::: "memory");   // tile 31 landed
        QKV_BAR();
        V_COMPUTE(1);                                      // tile 31

        float* Vp = Vpart + (size_t)kslice * 2048 * 1024;
#pragma unroll
        for (int i = 0; i < 4; i++) {
            const int row = bm0 + wm + i * 16 + quad * 4;
#pragma unroll
            for (int j = 0; j < 4; j++) {
                const int col = bn0 + wn + j * 16 + l16;
#pragma unroll
                for (int r = 0; r < 4; r++)
                    Vp[(size_t)(row + r) * 1024 + col] = acc[i][j][r];
            }
        }
    }
}

// ---------------- O-projection GEMM: single-pass K=4096, depth-3 counted-vmcnt pipeline --------
// BM=256, BN=128, BK=64. 512 thr (8 waves, 4Mx2N, 64x64/wave). LDS: 3 x 48KB buffers (dynamic).
// Stage uses inverse-swizzled global source (linear LDS dest); ds_read applies slot^=(row&7)
// -> conflict-free b128 batches. vmcnt(12) steady state (2 tiles in flight), peel 12->6->0.
// Direct fp32 store to d_out: no split-K, no atomics, no memset, no reduce.

#define GO_STAGE(bufi, kt) do {                                                   \
    u16* la_ = S + (bufi) * 24576;                                                \
    u16* lb_ = la_ + 16384;                                                       \
    const int k0_ = (kt) * 64;                                                    \
    _Pragma("unroll")                                                             \
    for (int u = 0; u < 4; u++)                                                   \
        async_copy16(Asrc + (size_t)u * 64 * 4096 + k0_, la_ + u * 4096 + sdst);  \
    _Pragma("unroll")                                                             \
    for (int u = 0; u < 2; u++)                                                   \
        async_copy16(Bsrc + (size_t)u * 64 * 4096 + k0_, lb_ + u * 4096 + sdst);  \
} while (0)

#define GO_COMPUTE(bufi) do {                                                     \
    const u16* la_ = S + (bufi) * 24576;                                          \
    const u16* lb_ = la_ + 16384;                                                 \
    bf16x8 bfr[4][2], afr[2][2];                                                  \
    _Pragma("unroll")                                                             \
    for (int j = 0; j < 4; j++) {                                                 \
        const int rb_ = (wn + j * 16 + l16) * 64;                                 \
        bfr[j][0] = *(const bf16x8*)&lb_[rb_ + o0];                               \
        bfr[j][1] = *(const bf16x8*)&lb_[rb_ + o1];                               \
    }                                                                             \
    _Pragma("unroll")                                                             \
    for (int i = 0; i < 2; i++) {                                                 \
        const int ra_ = (wm + i * 16 + l16) * 64;                                 \
        afr[i][0] = *(const bf16x8*)&la_[ra_ + o0];                               \
        afr[i][1] = *(const bf16x8*)&la_[ra_ + o1];                               \
    }                                                                             \
    asm volatile("s_waitcnt lgkmcnt(0)" ::: "memory");                            \
    __builtin_amdgcn_sched_barrier(0);                                            \
    __builtin_amdgcn_s_setprio(1);                                                \
    _Pragma("unroll")                                                             \
    for (int i = 0; i < 2; i++)                                                   \
        _Pragma("unroll")                                                         \
        for (int j = 0; j < 4; j++) {                                             \
            acc[i][j] = __builtin_amdgcn_mfma_f32_16x16x32_bf16(afr[i][0], bfr[j][0], acc[i][j], 0, 0, 0); \
            acc[i][j] = __builtin_amdgcn_mfma_f32_16x16x32_bf16(afr[i][1], bfr[j][1], acc[i][j], 0, 0, 0); \
        }                                                                         \
    __builtin_amdgcn_s_setprio(0);                                                \
    _Pragma("unroll")                                                             \
    for (int i = 0; i < 2; i++) {                                                 \
        const int ra_ = (wm + (i + 2) * 16 + l16) * 64;                           \
        afr[i][0] = *(const bf16x8*)&la_[ra_ + o0];                               \
        afr[i][1] = *(const bf16x8*)&la_[ra_ + o1];                               \
    }                                                                             \
    asm volatile("s_waitcnt lgkmcnt(0)" ::: "memory");                            \
    __builtin_amdgcn_sched_barrier(0);                                            \
    __builtin_amdgcn_s_setprio(1);                                                \
    _Pragma("unroll")                                                             \
    for (int i = 0; i < 2; i++)                                                   \
        _Pragma("unroll")                                                         \
        for (int j = 0; j < 4; j++) {                                             \
            acc[i + 2][j] = __builtin_amdgcn_mfma_f32_16x16x32_bf16(afr[i][0], bfr[j][0], acc[i + 2][j], 0, 0, 0); \
            acc[i + 2][j] = __builtin_amdgcn_mfma_f32_16x16x32_bf16(afr[i][1], bfr[j][1], acc[i + 2][j], 0, 0, 0); \
        }                                                                         \
    __builtin_amdgcn_s_setprio(0);                                                \
} while (0)

#define GO_BAR() asm volatile("s_barrier" ::: "memory")

__global__ __launch_bounds__(512, 2) void gemm_o_k(const u16* __restrict__ A,
                                                   const u16* __restrict__ B,
                                                   float* __restrict__ Out) {
    extern __shared__ u16 S[];                 // 3 * 49152 B = 144 KB
    const int tid = threadIdx.x;
    const int w = tid >> 6, lane = tid & 63;
    const int quad = lane >> 4, l16 = lane & 15;
    // XCD-bijective swizzle over 256 blocks: each XCD gets one contiguous m-row (A-panel L2-resident)
    const int linear = blockIdx.y * 32 + blockIdx.x;
    const int wgid = (linear & 7) * 32 + (linear >> 3);
    const int bm0 = (wgid >> 5) * 256;
    const int bn0 = (wgid & 31) * 128;
    const int wm = (w >> 1) * 64;              // 4 waves along M
    const int wn = (w & 1) * 64;               // 2 waves along N
    // staging: thread -> (row = u*64 + tid>>3, col16B = (tid&7) ^ (row&7))  [inverse swizzle]
    const int sr = tid >> 3;
    const int scg = ((tid & 7) ^ (sr & 7)) * 8;
    const int sdst = tid * 8;                  // u16 units (16B/thread)
    const u16* Asrc = A + (size_t)(bm0 + sr) * 4096 + scg;
    const u16* Bsrc = B + (size_t)(bn0 + sr) * 4096 + scg;
    // fragment read swizzle: slot = ((kk<<2)|quad) ^ (row&7); row&7 == l16&7 here
    const int swz = l16 & 7;
    const int o0 = (quad ^ swz) * 8;           // u16 offset for kk=0
    const int o1 = ((4 | quad) ^ swz) * 8;     // u16 offset for kk=1

    f32x4 acc[4][4] = {};

    GO_STAGE(0, 0);
    GO_STAGE(1, 1);
    GO_STAGE(2, 2);
    asm volatile("s_waitcnt vmcnt(12)" ::: "memory");   // tile 0 landed
    GO_BAR();

    int cur = 0;
    for (int t = 0; t < 61; ++t) {
        GO_COMPUTE(cur);
        GO_BAR();                                        // all waves done reading buf[cur]
        GO_STAGE(cur, t + 3);
        asm volatile("s_waitcnt vmcnt(12)" ::: "memory"); // tile t+1 landed (t+2,t+3 in flight)
        GO_BAR();
        cur = (cur == 2) ? 0 : cur + 1;
    }
    // t = 61 (buf 1): tile 63's 6 loads may still be in flight
    GO_COMPUTE(1);
    asm volatile("s_waitcnt vmcnt(6)" ::: "memory");      // tile 62 landed
    GO_BAR();
    // t = 62 (buf 2)
    GO_COMPUTE(2);
    asm volatile("s_waitcnt vmcnt(0)" ::: "memory");      // tile 63 landed
    GO_BAR();
    // t = 63 (buf 0)
    GO_COMPUTE(0);

#pragma unroll
    for (int i = 0; i < 4; i++) {
        const int row = bm0 + wm + i * 16 + quad * 4;
#pragma unroll
        for (int j = 0; j < 4; j++) {
            const int col = bn0 + wn + j * 16 + l16;
#pragma unroll
            for (int r = 0; r < 4; r++)
                Out[(size_t)(row + r) * 4096 + col] = acc[i][j][r];
        }
    }
}

// ---------------- fused flash attention (GQA, causal, no-max softmax) ----------------
// 8 waves x 16 q-rows (512 thr). Grid (32 heads, 8): each block processes the q-tile
// PAIR (15-y, y) sequentially -> uniform 34 k-tiles/block, 256 blocks = 1/CU, no tail.
// NEW: double-buffered K/V staging with counted vmcnt(4) (never 0 in the tile loop),
// and slot-swizzled K/V LDS (phys 16B-slot = logical ^ ((row>>1)&3)) via inverse-
// swizzled global source + swizzled fragment reads -> 8-way bank conflict -> 2-way.

#define ATT_STAGE(bufi, g) do {                                                   \
    const size_t go_ = (size_t)(g) * 64;                                          \
    async_copy16(kbase0 + go_ * kstride, ldk0[bufi]);                             \
    async_copy16(kbase1 + go_ * kstride, ldk1[bufi]);                             \
    async_copy16(vbase0 + go_, ldv0[bufi]);                                       \
    async_copy16(vbase1 + go_, ldv1[bufi]);                                       \
} while (0)

#define ATT_COMPUTE(bufi, g0) do {                                                \
    if ((g0) <= wrow + 15) {                                                      \
        const u16* lK_ = ldsK[bufi];                                              \
        const u16* lV_ = ldsV[bufi];                                              \
        f32x4 accs[4] = {};                                                       \
        _Pragma("unroll")                                                         \
        for (int kk = 0; kk < 4; kk++) {                                          \
            bf16x8 bfrag[4];                                                      \
            _Pragma("unroll")                                                     \
            for (int ni = 0; ni < 4; ni++)                                        \
                bfrag[ni] = *(const bf16x8*)&lK_[kk * 2048 + (ni * 16 + l16) * 32 + sswz]; \
            __builtin_amdgcn_s_setprio(1);                                        \
            _Pragma("unroll")                                                     \
            for (int ni = 0; ni < 4; ni++)                                        \
                accs[ni] = __builtin_amdgcn_mfma_f32_16x16x32_bf16(               \
                    qf[kk], bfrag[ni], accs[ni], 0, 0, 0);                        \
            __builtin_amdgcn_s_setprio(0);                                        \
        }                                                                         \
        const bool diag = ((g0) + 63 > wrow);                                     \
        int kidx[4];                                                              \
        _Pragma("unroll")                                                         \
        for (int ni = 0; ni < 4; ni++) kidx[ni] = (g0) + ni * 16 + l16;           \
        _Pragma("unroll")                                                         \
        for (int r = 0; r < 4; r++) {                                             \
            const int qrow = wrow + quad * 4 + r;                                 \
            float p[4];                                                           \
            _Pragma("unroll")                                                     \
            for (int ni = 0; ni < 4; ni++) {                                      \
                float s = accs[ni][r];                                            \
                if (diag && (kidx[ni] > qrow)) s = -1e30f;                        \
                p[ni] = __builtin_amdgcn_exp2f(s);                                \
            }                                                                     \
            lrow[r] += (p[0] + p[1]) + (p[2] + p[3]);                             \
            uint2 pk;                                                             \
            pk.x = pack_bf2(p[0], p[1]);                                          \
            pk.y = pack_bf2(p[2], p[3]);                                          \
            *(uint2*)&ldsP[w][(quad * 4 + r) * 72 + l16 * 4] = pk;                \
        }                                                                         \
        _Pragma("unroll")                                                         \
        for (int ks = 0; ks < 2; ks++) {                                          \
            bf16x8 pa = *(const bf16x8*)&ldsP[w][l16 * 72 + ks * 32 + quad * 8];  \
            __builtin_amdgcn_s_setprio(1);                                        \
            _Pragma("unroll")                                                     \
            for (int oj = 0; oj < 8; oj++) {                                      \
                bf16x8 vb = *(const bf16x8*)&lV_[ks * 4096 + (oj * 16 + l16) * 32 + sswz]; \
                acc_o[oj] = __builtin_amdgcn_mfma_f32_16x16x32_bf16(              \
                    pa, vb, acc_o[oj], 0, 0, 0);                                  \
            }                                                                     \
            __builtin_amdgcn_s_setprio(0);                                        \
        }                                                                         \
    }                                                                             \
} while (0)

__global__ __launch_bounds__(512) void attn_k(const u16* __restrict__ Qb,
                                              const u16* __restrict__ Kb,
                                              const u16* __restrict__ Vt,
                                              u16* __restrict__ Ob,
                                              int qstride, int kstride) {
    __shared__ u16 ldsK[2][4 * 64 * 32];   // dbuf [kk][key][hd32], slot-swizzled
    __shared__ u16 ldsV[2][2 * 128 * 32];  // dbuf [ks][d][kappa32], slot-swizzled
    __shared__ u16 ldsP[8][16 * 72];       // per-wave [m 16][kappa 64 + pad 8]
    const int h = blockIdx.x;
    const int kvh = h >> 2;
    const int tid = threadIdx.x;
    const int w = tid >> 6, lane = tid & 63;
    const int quad = lane >> 4, l16 = lane & 15;
    // fragment-read slot swizzle: phys slot = quad ^ ((row>>1)&3), row%16 == l16
    const int sswz = (quad ^ ((l16 >> 1) & 3)) * 8;

    // staging: 32 chunks (16 K + 16 V), 4 per wave; global source inverse-swizzled:
    // chunk row = lane>>2, 16B-block = (lane&3) ^ ((lane>>3)&3)
    const int cblk = (lane & 3) ^ ((lane >> 3) & 3);
    const int wlA = w, wlB = w + 8;
    const u16* kbase0 = Kb + (size_t)((wlA & 3) * 16 + (lane >> 2)) * kstride + kvh * 128 + (wlA >> 2) * 32 + cblk * 8;
    const u16* kbase1 = Kb + (size_t)((wlB & 3) * 16 + (lane >> 2)) * kstride + kvh * 128 + (wlB >> 2) * 32 + cblk * 8;
    const u16* vbase0 = Vt + (size_t)(kvh * 128 + (wlA & 7) * 16 + (lane >> 2)) * 2048 + (wlA >> 3) * 32 + cblk * 8;
    const u16* vbase1 = Vt + (size_t)(kvh * 128 + (wlB & 7) * 16 + (lane >> 2)) * 2048 + (wlB >> 3) * 32 + cblk * 8;
    u16* ldk0[2]; u16* ldk1[2]; u16* ldv0[2]; u16* ldv1[2];
#pragma unroll
    for (int b = 0; b < 2; b++) {
        ldk0[b] = &ldsK[b][wlA * 512];
        ldk1[b] = &ldsK[b][wlB * 512];
        ldv0[b] = &ldsV[b][wlA * 512];
        ldv1[b] = &ldsV[b][wlB * 512];
    }

#pragma unroll
    for (int ph = 0; ph < 2; ph++) {
        const int qt = ph == 0 ? (15 - (int)blockIdx.y) : (int)blockIdx.y;
        const int q0 = qt * 128;
        const int wrow = q0 + w * 16;

        bf16x8 qf[4];
#pragma unroll
        for (int kk = 0; kk < 4; kk++)
            qf[kk] = *(const bf16x8*)&Qb[(size_t)(wrow + l16) * qstride +
                                         h * 128 + kk * 32 + quad * 8];

        f32x4 acc_o[8] = {};
        float lrow[4] = {};

        const int nk = 2 * (qt + 1);
        ATT_STAGE(0, 0);
        ATT_STAGE(1, 1);
        asm volatile("s_waitcnt vmcnt(4)" ::: "memory");   // tile 0 landed
        QKV_BAR();
        int cur = 0;
        for (int kn = 0; kn < nk - 2; kn++) {
            ATT_COMPUTE(cur, kn * 64);
            QKV_BAR();                                     // all waves done reading buf[cur]
            ATT_STAGE(cur, kn + 2);
            asm volatile("s_waitcnt vmcnt(4)" ::: "memory"); // tile kn+1 landed
            QKV_BAR();
            cur ^= 1;
        }
        ATT_COMPUTE(cur, (nk - 2) * 64);
        asm volatile("s_waitcnt vmcnt(0)" ::: "memory");   // last tile landed
        QKV_BAR();
        ATT_COMPUTE(cur ^ 1, (nk - 1) * 64);

#pragma unroll
        for (int r = 0; r < 4; r++) {
            float l = lrow[r];
            l += __shfl_xor(l, 1);
            l += __shfl_xor(l, 2);
            l += __shfl_xor(l, 4);
            l += __shfl_xor(l, 8);
            const float inv = 1.0f / l;
            const int qrow = wrow + quad * 4 + r;
#pragma unroll
            for (int oj = 0; oj < 8; oj++)
                Ob[(size_t)qrow * 4096 + h * 128 + oj * 16 + l16] =
                    f2bf(acc_o[oj][r] * inv);
        }
        QKV_BAR();   // next phase's staging must not race this phase's reads
    }
}

// ---------------- launch ----------------

extern "C" void kernel_launch(void* const* d_in, const int* in_sizes, int n_in,
                              void* d_out, int out_size, void* d_ws, size_t ws_size,
                              hipStream_t stream) {
    (void)in_sizes; (void)n_in; (void)out_size; (void)ws_size;
    const float* hidden = (const float*)d_in[0];
    const float* Wq = (const float*)d_in[1];
    const float* Wk = (const float*)d_in[2];
    const float* Wv = (const float*)d_in[3];
    const float* Wo = (const float*)d_in[4];
    const float* cosv = (const float*)d_in[5];
    const float* sinv = (const float*)d_in[6];
    const int* qoc = (const int*)d_in[8];
    const int* qor = (const int*)d_in[9];
    const int* koc = (const int*)d_in[10];
    const int* kor = (const int*)d_in[11];
    const int* voc = (const int*)d_in[12];
    const int* vor = (const int*)d_in[13];
    const int* ooc = (const int*)d_in[14];
    const int* oor = (const int*)d_in[15];

    char* ws = (char*)d_ws;
    size_t off = 0;
    // persistent across the whole pipeline:
    int* invq = (int*)(ws + off); off += 16384;
    int* invk = (int*)(ws + off); off += 16384;
    int* invv = (int*)(ws + off); off += 16384;
    int* invo = (int*)(ws + off); off += 16384;
    u16* Wop   = (u16*)(ws + off); off += (size_t)4096 * 4096 * 2;   // 33.5 MB (live at O-proj)
    u16* Xb    = (u16*)(ws + off); off += (size_t)2048 * 4096 * 2;   // 16.8 MB (live as Attb)
    u8*  Wqkf8 = (u8*)(ws + off);  off += (size_t)5120 * 4096;       // 21.0 MB
    u16* Wvp   = (u16*)(ws + off); off += (size_t)1024 * 4096 * 2;   //  8.4 MB
    u8*  Xf8   = (u8*)(ws + off);  off += (size_t)2048 * 4096;       //  8.4 MB
    u16* QKVb  = (u16*)(ws + off); off += (size_t)2048 * 6144 * 2;   // 25.2 MB
    u16* Vtb   = (u16*)(ws + off); off += (size_t)1024 * 2048 * 2;   //  4.2 MB
    float* Vpart = (float*)(ws + off); off += (size_t)2 * 2048 * 1024 * 4;  // 16.8 MB
    u16* Attb  = Xb;   // Xb dead after gemm_qkv_k; reuse for attention output

    inv4_k<<<64, 256, 0, stream>>>(qoc, koc, voc, ooc, invq, invk, invv, invo);
    permw4_k<<<10240, 256, 0, stream>>>(Wq, Wk, Wv, Wo, qor, kor, vor, oor,
                                        invq, invk, invv, invo, Wqkf8, Wvp, Wop);
    cvt_k<<<2048, 256, 0, stream>>>(hidden, Xb, Xf8);

    // QKV: Q,K via MX-fp8 (+fused RoPE/scale/log2e) + V via bf16 split-K2 -> QKVb + Vpart
    gemm_qkv_k<<<dim3(56, 16), 256, 65536, stream>>>(Xf8, Xb, Wqkf8, Wvp, QKVb, Vpart,
                                                     cosv, sinv);

    // Vt build (sums split-K partials, kappa permutation)
    vtr_k<<<512, 256, 0, stream>>>(Vpart, Vtb);

    // attention -> Attb [2048][4096]  (reuses Xb storage)
    attn_k<<<dim3(32, 8), 512, 0, stream>>>(QKVb, QKVb + 4096, Vtb, Attb, 6144, 6144);

    // O-projection: single-pass pipelined bf16 GEMM, direct fp32 store
    gemm_o_k<<<dim3(32, 8), 512, 147456, stream>>>(Attb, Wop, (float*)d_out);
}